// Round 1
// baseline (1308.907 us; speedup 1.0000x reference)
//
#include <hip/hip_runtime.h>

// MetaLA decoder layer on gfx950.
// Pipeline: LN1 -> causal depthwise conv4+SiLU -> fused QKVG GEMM (bf16 MFMA)
//  -> gate calc -> chunked GLA scan (3 passes, fp32) -> aug+groupnorm+gate
//  -> out GEMM (+residual, transpose) -> LN2 -> GLU GEMMs -> output (+x1).
// All GEMMs: bf16 inputs (A row-major MxK, B as N x K i.e. W^T), fp32 accum.

#define Lseq 2048
#define Bb 4
#define Dd 1024
#define Hh 16
#define DKk 512
#define GLUD 2816
#define NC 16
#define CHK 128
#define SUB 16

typedef float f32x4 __attribute__((ext_vector_type(4)));
typedef __bf16 bf16x8 __attribute__((ext_vector_type(8)));
typedef unsigned short u16;
typedef u16 u16x8 __attribute__((ext_vector_type(8)));

__device__ __forceinline__ u16 f2bf(float f) {
  unsigned int u = __float_as_uint(f);
  u += 0x7fffu + ((u >> 16) & 1u);
  return (u16)(u >> 16);
}

__device__ __forceinline__ float block_sum(float v, float* red) {
#pragma unroll
  for (int o = 32; o > 0; o >>= 1) v += __shfl_down(v, o);
  __syncthreads();
  if ((threadIdx.x & 63) == 0) red[threadIdx.x >> 6] = v;
  __syncthreads();
  return red[0] + red[1] + red[2] + red[3];
}

// ---------------- LN1: x (L,B,D) -> h (B,L,D) fp32 ----------------
__global__ __launch_bounds__(256) void ln1_k(const float* __restrict__ x,
                                             const float* __restrict__ w,
                                             const float* __restrict__ bia,
                                             float* __restrict__ h) {
  __shared__ float red[4];
  int r = blockIdx.x;           // r = l*B + b
  int l = r >> 2, bb = r & 3;
  const float* xr = x + (size_t)r * Dd;
  int d0 = threadIdx.x * 4;
  float4 xv = *(const float4*)&xr[d0];
  float mean = block_sum(xv.x + xv.y + xv.z + xv.w, red) * (1.f / Dd);
  float a0 = xv.x - mean, a1 = xv.y - mean, a2 = xv.z - mean, a3 = xv.w - mean;
  float var = block_sum(a0 * a0 + a1 * a1 + a2 * a2 + a3 * a3, red) * (1.f / Dd);
  float rs = rsqrtf(var + 1e-5f);
  float4 ov;
  ov.x = a0 * rs * w[d0 + 0] + bia[d0 + 0];
  ov.y = a1 * rs * w[d0 + 1] + bia[d0 + 1];
  ov.z = a2 * rs * w[d0 + 2] + bia[d0 + 2];
  ov.w = a3 * rs * w[d0 + 3] + bia[d0 + 3];
  *(float4*)&h[((size_t)(bb * Lseq + l)) * Dd + d0] = ov;
}

// ---------------- LN2: x1 (row r) -> z bf16 (row r) ----------------
__global__ __launch_bounds__(256) void ln2_k(const float* __restrict__ x1,
                                             const float* __restrict__ w,
                                             const float* __restrict__ bia,
                                             u16* __restrict__ z) {
  __shared__ float red[4];
  int r = blockIdx.x;
  const float* xr = x1 + (size_t)r * Dd;
  int d0 = threadIdx.x * 4;
  float4 xv = *(const float4*)&xr[d0];
  float mean = block_sum(xv.x + xv.y + xv.z + xv.w, red) * (1.f / Dd);
  float a0 = xv.x - mean, a1 = xv.y - mean, a2 = xv.z - mean, a3 = xv.w - mean;
  float var = block_sum(a0 * a0 + a1 * a1 + a2 * a2 + a3 * a3, red) * (1.f / Dd);
  float rs = rsqrtf(var + 1e-5f);
  ushort4 o;
  o.x = f2bf(a0 * rs * w[d0 + 0] + bia[d0 + 0]);
  o.y = f2bf(a1 * rs * w[d0 + 1] + bia[d0 + 1]);
  o.z = f2bf(a2 * rs * w[d0 + 2] + bia[d0 + 2]);
  o.w = f2bf(a3 * rs * w[d0 + 3] + bia[d0 + 3]);
  *(ushort4*)&z[(size_t)r * Dd + d0] = o;
}

// ------------- conv4 causal + SiLU: h (B,L,D) -> y bf16 (B*L, D) -------------
__global__ __launch_bounds__(256) void conv_k(const float* __restrict__ h,
                                              const float* __restrict__ cw,
                                              u16* __restrict__ ybf) {
  int m = blockIdx.x;           // m = b*L + l
  int b = m >> 11, l = m & (Lseq - 1);
  int d0 = threadIdx.x * 4;
  float4 acc = {0.f, 0.f, 0.f, 0.f};
  const float* hb = h + ((size_t)b * Lseq) * Dd + d0;
#pragma unroll
  for (int w = 0; w < 4; w++) {
    int ll = l - 3 + w;
    if (ll >= 0) {
      float4 hv = *(const float4*)&hb[(size_t)ll * Dd];
      acc.x += hv.x * cw[(d0 + 0) * 4 + w];
      acc.y += hv.y * cw[(d0 + 1) * 4 + w];
      acc.z += hv.z * cw[(d0 + 2) * 4 + w];
      acc.w += hv.w * cw[(d0 + 3) * 4 + w];
    }
  }
  ushort4 o;
  o.x = f2bf(acc.x / (1.f + expf(-acc.x)));
  o.y = f2bf(acc.y / (1.f + expf(-acc.y)));
  o.z = f2bf(acc.z / (1.f + expf(-acc.z)));
  o.w = f2bf(acc.w / (1.f + expf(-acc.w)));
  *(ushort4*)&ybf[(size_t)m * Dd + d0] = o;
}

// -------- transpose + fp32->bf16: dst[(c*mult+off)*R + r] = bf16(src[r*C+c]) --------
__global__ __launch_bounds__(256) void transpose_bf16(const float* __restrict__ src,
                                                      u16* __restrict__ dst,
                                                      int R, int C, int mult, int off) {
  __shared__ float tile[32][33];
  int tx = threadIdx.x & 31, ty = threadIdx.x >> 5;  // 32x8
  int c0 = blockIdx.x * 32, r0 = blockIdx.y * 32;
#pragma unroll
  for (int k = 0; k < 4; k++)
    tile[ty + 8 * k][tx] = src[(size_t)(r0 + ty + 8 * k) * C + c0 + tx];
  __syncthreads();
#pragma unroll
  for (int k = 0; k < 4; k++) {
    int c = c0 + ty + 8 * k;
    dst[(size_t)(c * mult + off) * R + r0 + tx] = f2bf(tile[tx][ty + 8 * k]);
  }
}

// ---------------- decay / k from kg ----------------
__global__ __launch_bounds__(256) void gate_k(const float* __restrict__ qkvg,
                                              float* __restrict__ decay,
                                              float* __restrict__ kk) {
  int idx = blockIdx.x * 256 + threadIdx.x;  // < 8192*512
  int m = idx >> 9, d = idx & 511;
  float kg = qkvg[(size_t)m * 3072 + 512 + d];
  float s = 1.f / (1.f + expf(-kg));
  float dec = expf(0.0625f * logf(s));  // exp(log_sigmoid(kg)/16)
  decay[idx] = dec;
  kk[idx] = 1.f - dec;
}

// ---------------- pass A: per-chunk T (32x64) and decay product P (32) ----------------
__global__ __launch_bounds__(64) void passA_k(const float* __restrict__ decay,
                                              const float* __restrict__ kk,
                                              const float* __restrict__ qkvg,
                                              float* __restrict__ T,
                                              float* __restrict__ P) {
  __shared__ __align__(16) float se[SUB * 32], sk[SUB * 32], sv[SUB * 64];
  int c = blockIdx.x, bh = blockIdx.y;
  int b = bh >> 4, h = bh & 15;
  int lane = threadIdx.x;
  size_t bL = (size_t)b * Lseq;
  int h32 = h * 32, h64 = h * 64;
  float S[32];
#pragma unroll
  for (int i = 0; i < 32; i++) S[i] = 0.f;
  float p = 1.f;
  int l0 = c * CHK;
  for (int s0 = 0; s0 < CHK; s0 += SUB) {
    __syncthreads();
#pragma unroll
    for (int t = 0; t < 2; t++) {
      int fi = t * 64 + lane;
      int ts = fi >> 3, i4 = (fi & 7) * 4;
      size_t g = (bL + l0 + s0 + ts) * 512 + h32 + i4;
      *(float4*)&se[fi * 4] = *(const float4*)&decay[g];
      *(float4*)&sk[fi * 4] = *(const float4*)&kk[g];
    }
#pragma unroll
    for (int t = 0; t < 4; t++) {
      int fi = t * 64 + lane;
      int ts = fi >> 4, j4 = (fi & 15) * 4;
      *(float4*)&sv[fi * 4] =
          *(const float4*)&qkvg[(bL + l0 + s0 + ts) * 3072 + 1024 + h64 + j4];
    }
    __syncthreads();
    for (int ts = 0; ts < SUB; ts++) {
      float vj = sv[ts * 64 + lane];
#pragma unroll
      for (int i = 0; i < 32; i += 4) {
        float4 e4 = *(const float4*)&se[ts * 32 + i];
        float4 k4 = *(const float4*)&sk[ts * 32 + i];
        S[i + 0] = e4.x * S[i + 0] + k4.x * vj;
        S[i + 1] = e4.y * S[i + 1] + k4.y * vj;
        S[i + 2] = e4.z * S[i + 2] + k4.z * vj;
        S[i + 3] = e4.w * S[i + 3] + k4.w * vj;
      }
      if (lane < 32) p *= se[ts * 32 + lane];
    }
  }
  float* Tc = T + ((size_t)bh * NC + c) * 2048;
#pragma unroll
  for (int i = 0; i < 32; i++) Tc[i * 64 + lane] = S[i];
  if (lane < 32) P[((size_t)bh * NC + c) * 32 + lane] = p;
}

// ---------------- pass B: sequential cross-chunk state propagation ----------------
__global__ __launch_bounds__(256) void passB_k(const float* __restrict__ T,
                                               const float* __restrict__ P,
                                               float* __restrict__ Sg) {
  int bh = blockIdx.x;
  int tid = threadIdx.x;
  int f = tid * 8, i = f >> 6;
  float s[8];
#pragma unroll
  for (int e = 0; e < 8; e++) s[e] = 0.f;
  for (int c = 0; c < NC; c++) {
    size_t base = ((size_t)bh * NC + c) * 2048 + f;
    float pc = P[((size_t)bh * NC + c) * 32 + i];
#pragma unroll
    for (int e = 0; e < 8; e++) {
      Sg[base + e] = s[e];                 // state at chunk start
      s[e] = pc * s[e] + T[base + e];
    }
  }
}

// ---------------- pass C: chunk-local scan with injected start state ----------------
__global__ __launch_bounds__(64) void passC_k(const float* __restrict__ decay,
                                              const float* __restrict__ kk,
                                              const float* __restrict__ qkvg,
                                              const float* __restrict__ Sg,
                                              float* __restrict__ osc) {
  __shared__ __align__(16) float se[SUB * 32], sk[SUB * 32], sq[SUB * 32], sv[SUB * 64];
  int c = blockIdx.x, bh = blockIdx.y;
  int b = bh >> 4, h = bh & 15;
  int lane = threadIdx.x;
  size_t bL = (size_t)b * Lseq;
  int h32 = h * 32, h64 = h * 64;
  float S[32];
  const float* Sgc = Sg + ((size_t)bh * NC + c) * 2048;
#pragma unroll
  for (int i = 0; i < 32; i++) S[i] = Sgc[i * 64 + lane];
  int l0 = c * CHK;
  for (int s0 = 0; s0 < CHK; s0 += SUB) {
    __syncthreads();
#pragma unroll
    for (int t = 0; t < 2; t++) {
      int fi = t * 64 + lane;
      int ts = fi >> 3, i4 = (fi & 7) * 4;
      size_t g = (bL + l0 + s0 + ts) * 512 + h32 + i4;
      *(float4*)&se[fi * 4] = *(const float4*)&decay[g];
      *(float4*)&sk[fi * 4] = *(const float4*)&kk[g];
      *(float4*)&sq[fi * 4] = *(const float4*)&qkvg[(bL + l0 + s0 + ts) * 3072 + h32 + i4];
    }
#pragma unroll
    for (int t = 0; t < 4; t++) {
      int fi = t * 64 + lane;
      int ts = fi >> 4, j4 = (fi & 15) * 4;
      *(float4*)&sv[fi * 4] =
          *(const float4*)&qkvg[(bL + l0 + s0 + ts) * 3072 + 1024 + h64 + j4];
    }
    __syncthreads();
    for (int ts = 0; ts < SUB; ts++) {
      float vj = sv[ts * 64 + lane];
      float acc = 0.f;
#pragma unroll
      for (int i = 0; i < 32; i += 4) {
        float4 e4 = *(const float4*)&se[ts * 32 + i];
        float4 k4 = *(const float4*)&sk[ts * 32 + i];
        float4 q4 = *(const float4*)&sq[ts * 32 + i];
        S[i + 0] = e4.x * S[i + 0] + k4.x * vj; acc += q4.x * S[i + 0];
        S[i + 1] = e4.y * S[i + 1] + k4.y * vj; acc += q4.y * S[i + 1];
        S[i + 2] = e4.z * S[i + 2] + k4.z * vj; acc += q4.z * S[i + 2];
        S[i + 3] = e4.w * S[i + 3] + k4.w * vj; acc += q4.w * S[i + 3];
      }
      osc[(bL + l0 + s0 + ts) * 1024 + h64 + lane] = acc;
    }
  }
}

// -------- post-scan: aug sigmoid term + groupnorm(64) + silu(g) gate -> bf16 --------
__global__ __launch_bounds__(256) void postscan_k(const float* __restrict__ osc,
                                                  const float* __restrict__ qkvg,
                                                  const float* __restrict__ kk,
                                                  const float* __restrict__ aug,
                                                  const float* __restrict__ gb,
                                                  u16* __restrict__ o2) {
  int m = blockIdx.x;
  int tid = threadIdx.x;
  int h = tid >> 4, t16 = tid & 15;
  int j0 = t16 * 4;
  size_t base = (size_t)m * 3072;
  float4 ov = *(const float4*)&osc[(size_t)m * 1024 + h * 64 + j0];
  int i0 = t16 * 2;
  float q0 = qkvg[base + h * 32 + i0], q1 = qkvg[base + h * 32 + i0 + 1];
  float kA = kk[(size_t)m * 512 + h * 32 + i0], kB = kk[(size_t)m * 512 + h * 32 + i0 + 1];
  float aw = q0 * aug[h * 32 + i0] * kA + q1 * aug[h * 32 + i0 + 1] * kB;
  aw += __shfl_xor(aw, 1); aw += __shfl_xor(aw, 2);
  aw += __shfl_xor(aw, 4); aw += __shfl_xor(aw, 8);
  float4 vv = *(const float4*)&qkvg[base + 1024 + h * 64 + j0];
  ov.x += 1.f / (1.f + expf(-aw * vv.x));
  ov.y += 1.f / (1.f + expf(-aw * vv.y));
  ov.z += 1.f / (1.f + expf(-aw * vv.z));
  ov.w += 1.f / (1.f + expf(-aw * vv.w));
  float s = ov.x + ov.y + ov.z + ov.w;
  s += __shfl_xor(s, 1); s += __shfl_xor(s, 2);
  s += __shfl_xor(s, 4); s += __shfl_xor(s, 8);
  float mean = s * (1.f / 64.f);
  float d0 = ov.x - mean, d1 = ov.y - mean, d2 = ov.z - mean, d3 = ov.w - mean;
  float ss = d0 * d0 + d1 * d1 + d2 * d2 + d3 * d3;
  ss += __shfl_xor(ss, 1); ss += __shfl_xor(ss, 2);
  ss += __shfl_xor(ss, 4); ss += __shfl_xor(ss, 8);
  float rs = rsqrtf(ss * (1.f / 64.f) + 1e-5f);
  float4 gv = *(const float4*)&qkvg[base + 2048 + h * 64 + j0];
  float g0 = gv.x + gb[h * 64 + j0 + 0];
  float g1 = gv.y + gb[h * 64 + j0 + 1];
  float g2 = gv.z + gb[h * 64 + j0 + 2];
  float g3 = gv.w + gb[h * 64 + j0 + 3];
  ushort4 o;
  o.x = f2bf((g0 / (1.f + expf(-g0))) * d0 * rs);
  o.y = f2bf((g1 / (1.f + expf(-g1))) * d1 * rs);
  o.z = f2bf((g2 / (1.f + expf(-g2))) * d2 * rs);
  o.w = f2bf((g3 / (1.f + expf(-g3))) * d3 * rs);
  *(ushort4*)&o2[(size_t)m * 1024 + h * 64 + j0] = o;
}

// ---------------- bf16 MFMA GEMM: C(MxN) = A(MxK) * B(NxK)^T ----------------
// EPI 0: Cf[row*N+col] = v
// EPI 1: Cf[(l*B+b)*D+col] = v + addsrc[same]   (row = b*L+l; transpose to (L,B,D))
// EPI 2: Cf[row*D+col] = v + addsrc[same]
// EPI 3: GLU: even col=u1, odd col=u2 -> Cbf[row*(N/2) + col/2] = bf16(silu(u1)*u2)
template <int EPI>
__global__ __launch_bounds__(256) void gemm_bt(const u16* __restrict__ A,
                                               const u16* __restrict__ B,
                                               int M, int N, int K,
                                               float* __restrict__ Cf,
                                               const float* __restrict__ addsrc,
                                               u16* __restrict__ Cbf) {
  __shared__ __align__(16) u16 lA[128 * 40];  // +8 pad breaks bank aliasing
  __shared__ __align__(16) u16 lB[128 * 40];
  const int tid = threadIdx.x;
  const int wave = tid >> 6, lane = tid & 63;
  const int m0 = blockIdx.y * 128, n0 = blockIdx.x * 128;
  const int wm = wave & 1, wn = wave >> 1;
  f32x4 acc[4][4];
#pragma unroll
  for (int a = 0; a < 4; a++)
#pragma unroll
    for (int b = 0; b < 4; b++) acc[a][b] = {0.f, 0.f, 0.f, 0.f};

  const int row0 = tid >> 2;
  const int k8 = (tid & 3) * 8;
  for (int k0 = 0; k0 < K; k0 += 32) {
    __syncthreads();
#pragma unroll
    for (int it = 0; it < 2; it++) {
      int row = it * 64 + row0;
      u16x8 av = *(const u16x8*)(A + (size_t)(m0 + row) * K + k0 + k8);
      u16x8 bv = *(const u16x8*)(B + (size_t)(n0 + row) * K + k0 + k8);
      *(u16x8*)&lA[row * 40 + k8] = av;
      *(u16x8*)&lB[row * 40 + k8] = bv;
    }
    __syncthreads();
    const int kofs = (lane >> 4) * 8;
    const int rsel = lane & 15;
    bf16x8 af[4], bfr[4];
#pragma unroll
    for (int t = 0; t < 4; t++) {
      af[t] = __builtin_bit_cast(bf16x8, *(const u16x8*)&lA[(wm * 64 + t * 16 + rsel) * 40 + kofs]);
      bfr[t] = __builtin_bit_cast(bf16x8, *(const u16x8*)&lB[(wn * 64 + t * 16 + rsel) * 40 + kofs]);
    }
#pragma unroll
    for (int tm = 0; tm < 4; tm++)
#pragma unroll
      for (int tn = 0; tn < 4; tn++)
        acc[tm][tn] = __builtin_amdgcn_mfma_f32_16x16x32_bf16(af[tm], bfr[tn], acc[tm][tn], 0, 0, 0);
  }

  const int rquad = (lane >> 4) * 4;
  const int csel = lane & 15;
#pragma unroll
  for (int tm = 0; tm < 4; tm++) {
    int rowb = m0 + wm * 64 + tm * 16 + rquad;
#pragma unroll
    for (int tn = 0; tn < 4; tn++) {
      int col = n0 + wn * 64 + tn * 16 + csel;
#pragma unroll
      for (int r = 0; r < 4; r++) {
        float v = acc[tm][tn][r];
        int row = rowb + r;
        if (EPI == 0) {
          Cf[(size_t)row * N + col] = v;
        } else if (EPI == 1) {
          int l = row & (Lseq - 1), bb = row >> 11;
          size_t o = ((size_t)(l * Bb + bb)) * Dd + col;
          Cf[o] = v + addsrc[o];
        } else if (EPI == 2) {
          size_t o = (size_t)row * Dd + col;
          Cf[o] = v + addsrc[o];
        } else {
          float partner = __shfl_xor(v, 1);
          if ((lane & 1) == 0) {
            float p = (v / (1.f + expf(-v))) * partner;
            Cbf[(size_t)row * (N >> 1) + (col >> 1)] = f2bf(p);
          }
        }
      }
    }
  }
}

extern "C" void kernel_launch(void* const* d_in, const int* in_sizes, int n_in,
                              void* d_out, int out_size, void* d_ws, size_t ws_size,
                              hipStream_t stream) {
  const float* x = (const float*)d_in[0];
  const float* tn_w = (const float*)d_in[1];
  const float* tn_b = (const float*)d_in[2];
  const float* conv_w = (const float*)d_in[3];
  const float* q_w = (const float*)d_in[4];
  const float* kg_w = (const float*)d_in[5];
  const float* v_w = (const float*)d_in[6];
  const float* g_w = (const float*)d_in[7];
  const float* g_b = (const float*)d_in[8];
  const float* out_w = (const float*)d_in[9];
  const float* aug = (const float*)d_in[10];
  const float* cn_w = (const float*)d_in[11];
  const float* cn_b = (const float*)d_in[12];
  const float* l1_w = (const float*)d_in[13];
  const float* l2_w = (const float*)d_in[14];
  const float* l3_w = (const float*)d_in[15];
  float* out = (float*)d_out;
  char* ws = (char*)d_ws;

  // workspace layout (peak ~219 MB); regions reused across stage lifetimes
  u16* Wqkvg = (u16*)(ws + 0);                 // 6 MB   (3072 x 1024)
  u16* Wout = (u16*)(ws + 6291456);            // 2 MB
  u16* Wl12 = (u16*)(ws + 8388608);            // 11 MB  (5632 x 1024, interleaved)
  u16* Wl3 = (u16*)(ws + 19922944);            // 5.5 MB (1024 x 2816)
  float* hbuf = (float*)(ws + 25690112);       // 32 MB; reused as o_scan
  u16* ybf = (u16*)(ws + 59244544);            // 16 MB; reused as T then o2_bf
  float* Tbuf = (float*)(ws + 59244544);
  u16* o2bf = (u16*)(ws + 59244544);
  float* qkvg = (float*)(ws + 76021760);       // 96 MB; reused as x1/z/p
  float* x1 = (float*)(ws + 76021760);
  u16* zbf = (u16*)(ws + 109576192);
  u16* pbf = (u16*)(ws + 126353408);
  float* decay = (float*)(ws + 176685056);     // 16 MB
  float* kkb = (float*)(ws + 193462272);       // 16 MB
  float* Pbuf = (float*)(ws + 210239488);      // 128 KB
  float* Sg = (float*)(ws + 210370560);        // 8.4 MB
  float* osc = hbuf;

  dim3 b256(256);
  // weight prep (transpose + bf16 cast); l1/l2 interleaved for fused GLU epilogue
  transpose_bf16<<<dim3(16, 32), b256, 0, stream>>>(q_w, Wqkvg, 1024, 512, 1, 0);
  transpose_bf16<<<dim3(16, 32), b256, 0, stream>>>(kg_w, Wqkvg + 512 * 1024, 1024, 512, 1, 0);
  transpose_bf16<<<dim3(32, 32), b256, 0, stream>>>(v_w, Wqkvg + 1024 * 1024, 1024, 1024, 1, 0);
  transpose_bf16<<<dim3(32, 32), b256, 0, stream>>>(g_w, Wqkvg + 2048 * 1024, 1024, 1024, 1, 0);
  transpose_bf16<<<dim3(32, 32), b256, 0, stream>>>(out_w, Wout, 1024, 1024, 1, 0);
  transpose_bf16<<<dim3(88, 32), b256, 0, stream>>>(l1_w, Wl12, 1024, 2816, 2, 0);
  transpose_bf16<<<dim3(88, 32), b256, 0, stream>>>(l2_w, Wl12, 1024, 2816, 2, 1);
  transpose_bf16<<<dim3(32, 88), b256, 0, stream>>>(l3_w, Wl3, 2816, 1024, 1, 0);

  ln1_k<<<8192, b256, 0, stream>>>(x, tn_w, tn_b, hbuf);
  conv_k<<<8192, b256, 0, stream>>>(hbuf, conv_w, ybf);
  gemm_bt<0><<<dim3(24, 64), b256, 0, stream>>>(ybf, Wqkvg, 8192, 3072, 1024, qkvg, nullptr, nullptr);
  gate_k<<<16384, b256, 0, stream>>>(qkvg, decay, kkb);
  passA_k<<<dim3(NC, 64), 64, 0, stream>>>(decay, kkb, qkvg, Tbuf, Pbuf);
  passB_k<<<64, b256, 0, stream>>>(Tbuf, Pbuf, Sg);
  passC_k<<<dim3(NC, 64), 64, 0, stream>>>(decay, kkb, qkvg, Sg, osc);
  postscan_k<<<8192, b256, 0, stream>>>(osc, qkvg, kkb, aug, g_b, o2bf);
  gemm_bt<1><<<dim3(8, 64), b256, 0, stream>>>(o2bf, Wout, 8192, 1024, 1024, x1, x, nullptr);
  ln2_k<<<8192, b256, 0, stream>>>(x1, cn_w, cn_b, zbf);
  gemm_bt<3><<<dim3(44, 64), b256, 0, stream>>>(zbf, Wl12, 8192, 5632, 1024, nullptr, nullptr, pbf);
  gemm_bt<2><<<dim3(8, 64), b256, 0, stream>>>(pbf, Wl3, 8192, 1024, 2816, out, x1, nullptr);
}

// Round 2
// 755.571 us; speedup vs baseline: 1.7323x; 1.7323x over previous
//
#include <hip/hip_runtime.h>

// MetaLA decoder layer on gfx950.
// R2: (a) scan rewritten as SGPR-broadcast recurrence (e/k/q wave-uniform via
//     s_load, v per-lane; no LDS, no spill); (b) GEMM staging via
//     __builtin_amdgcn_global_load_lds width=16 (m97 pattern, unpadded tiles).

#define Lseq 2048
#define Bb 4
#define Dd 1024
#define Hh 16
#define GLUD 2816
#define NC 32
#define CHK 64

typedef float f32x4 __attribute__((ext_vector_type(4)));
typedef __bf16 bf16x8 __attribute__((ext_vector_type(8)));
typedef unsigned short u16;
typedef u16 u16x8 __attribute__((ext_vector_type(8)));

__device__ __forceinline__ u16 f2bf(float f) {
  unsigned int u = __float_as_uint(f);
  u += 0x7fffu + ((u >> 16) & 1u);
  return (u16)(u >> 16);
}

__device__ __forceinline__ void gll16(const void* g, void* l) {
  __builtin_amdgcn_global_load_lds((const __attribute__((address_space(1))) void*)g,
                                   (__attribute__((address_space(3))) void*)l, 16, 0, 0);
}

__device__ __forceinline__ float block_sum(float v, float* red) {
#pragma unroll
  for (int o = 32; o > 0; o >>= 1) v += __shfl_down(v, o);
  __syncthreads();
  if ((threadIdx.x & 63) == 0) red[threadIdx.x >> 6] = v;
  __syncthreads();
  return red[0] + red[1] + red[2] + red[3];
}

// ---------------- LN1: x (L,B,D) -> h (B,L,D) fp32 ----------------
__global__ __launch_bounds__(256) void ln1_k(const float* __restrict__ x,
                                             const float* __restrict__ w,
                                             const float* __restrict__ bia,
                                             float* __restrict__ h) {
  __shared__ float red[4];
  int r = blockIdx.x;           // r = l*B + b
  int l = r >> 2, bb = r & 3;
  const float* xr = x + (size_t)r * Dd;
  int d0 = threadIdx.x * 4;
  float4 xv = *(const float4*)&xr[d0];
  float mean = block_sum(xv.x + xv.y + xv.z + xv.w, red) * (1.f / Dd);
  float a0 = xv.x - mean, a1 = xv.y - mean, a2 = xv.z - mean, a3 = xv.w - mean;
  float var = block_sum(a0 * a0 + a1 * a1 + a2 * a2 + a3 * a3, red) * (1.f / Dd);
  float rs = rsqrtf(var + 1e-5f);
  float4 ov;
  ov.x = a0 * rs * w[d0 + 0] + bia[d0 + 0];
  ov.y = a1 * rs * w[d0 + 1] + bia[d0 + 1];
  ov.z = a2 * rs * w[d0 + 2] + bia[d0 + 2];
  ov.w = a3 * rs * w[d0 + 3] + bia[d0 + 3];
  *(float4*)&h[((size_t)(bb * Lseq + l)) * Dd + d0] = ov;
}

// ---------------- LN2: x1 (row r) -> z bf16 (row r) ----------------
__global__ __launch_bounds__(256) void ln2_k(const float* __restrict__ x1,
                                             const float* __restrict__ w,
                                             const float* __restrict__ bia,
                                             u16* __restrict__ z) {
  __shared__ float red[4];
  int r = blockIdx.x;
  const float* xr = x1 + (size_t)r * Dd;
  int d0 = threadIdx.x * 4;
  float4 xv = *(const float4*)&xr[d0];
  float mean = block_sum(xv.x + xv.y + xv.z + xv.w, red) * (1.f / Dd);
  float a0 = xv.x - mean, a1 = xv.y - mean, a2 = xv.z - mean, a3 = xv.w - mean;
  float var = block_sum(a0 * a0 + a1 * a1 + a2 * a2 + a3 * a3, red) * (1.f / Dd);
  float rs = rsqrtf(var + 1e-5f);
  ushort4 o;
  o.x = f2bf(a0 * rs * w[d0 + 0] + bia[d0 + 0]);
  o.y = f2bf(a1 * rs * w[d0 + 1] + bia[d0 + 1]);
  o.z = f2bf(a2 * rs * w[d0 + 2] + bia[d0 + 2]);
  o.w = f2bf(a3 * rs * w[d0 + 3] + bia[d0 + 3]);
  *(ushort4*)&z[(size_t)r * Dd + d0] = o;
}

// ------------- conv4 causal + SiLU: h (B,L,D) -> y bf16 (B*L, D) -------------
__global__ __launch_bounds__(256) void conv_k(const float* __restrict__ h,
                                              const float* __restrict__ cw,
                                              u16* __restrict__ ybf) {
  int m = blockIdx.x;           // m = b*L + l
  int b = m >> 11, l = m & (Lseq - 1);
  int d0 = threadIdx.x * 4;
  float4 acc = {0.f, 0.f, 0.f, 0.f};
  const float* hb = h + ((size_t)b * Lseq) * Dd + d0;
#pragma unroll
  for (int w = 0; w < 4; w++) {
    int ll = l - 3 + w;
    if (ll >= 0) {
      float4 hv = *(const float4*)&hb[(size_t)ll * Dd];
      acc.x += hv.x * cw[(d0 + 0) * 4 + w];
      acc.y += hv.y * cw[(d0 + 1) * 4 + w];
      acc.z += hv.z * cw[(d0 + 2) * 4 + w];
      acc.w += hv.w * cw[(d0 + 3) * 4 + w];
    }
  }
  ushort4 o;
  o.x = f2bf(acc.x / (1.f + expf(-acc.x)));
  o.y = f2bf(acc.y / (1.f + expf(-acc.y)));
  o.z = f2bf(acc.z / (1.f + expf(-acc.z)));
  o.w = f2bf(acc.w / (1.f + expf(-acc.w)));
  *(ushort4*)&ybf[(size_t)m * Dd + d0] = o;
}

// -------- transpose + fp32->bf16: dst[(c*mult+off)*R + r] = bf16(src[r*C+c]) --------
__global__ __launch_bounds__(256) void transpose_bf16(const float* __restrict__ src,
                                                      u16* __restrict__ dst,
                                                      int R, int C, int mult, int off) {
  __shared__ float tile[32][33];
  int tx = threadIdx.x & 31, ty = threadIdx.x >> 5;  // 32x8
  int c0 = blockIdx.x * 32, r0 = blockIdx.y * 32;
#pragma unroll
  for (int k = 0; k < 4; k++)
    tile[ty + 8 * k][tx] = src[(size_t)(r0 + ty + 8 * k) * C + c0 + tx];
  __syncthreads();
#pragma unroll
  for (int k = 0; k < 4; k++) {
    int c = c0 + ty + 8 * k;
    dst[(size_t)(c * mult + off) * R + r0 + tx] = f2bf(tile[tx][ty + 8 * k]);
  }
}

// ---------------- decay from kg ----------------
__global__ __launch_bounds__(256) void gate_k(const float* __restrict__ qkvg,
                                              float* __restrict__ decay) {
  int idx = blockIdx.x * 256 + threadIdx.x;  // < 8192*512
  int m = idx >> 9, d = idx & 511;
  float kg = qkvg[(size_t)m * 3072 + 512 + d];
  float s = 1.f / (1.f + expf(-kg));
  decay[idx] = expf(0.0625f * logf(s));  // exp(log_sigmoid(kg)/16)
}

// ---- pass A: per-chunk T (32x64) and decay product P (32); 4 waves = 4 chunks ----
// lane = j (v index). e/k wave-uniform -> SGPR loads; v coalesced vector load.
__global__ __launch_bounds__(256) void passA_k(const float* __restrict__ decay,
                                               const float* __restrict__ qkvg,
                                               float* __restrict__ T,
                                               float* __restrict__ P) {
  int wave = threadIdx.x >> 6, lane = threadIdx.x & 63;
  int c = blockIdx.x * 4 + wave, bh = blockIdx.y;
  int b = bh >> 4, h = bh & 15;
  size_t t0 = (size_t)b * Lseq + c * CHK;        // first timestep row
  const float* ep = decay + t0 * 512 + h * 32;   // uniform base
  const float* vp = qkvg + t0 * 3072 + 1024 + h * 64 + lane;
  const float* dp = decay + t0 * 512 + h * 32 + (lane & 31);
  float S[32];
#pragma unroll
  for (int i = 0; i < 32; i++) S[i] = 0.f;
  float p = 1.f;
  float vnext = vp[0], dnext = dp[0];
#pragma unroll 1
  for (int ts = 0; ts < CHK; ts++) {
    float vj = vnext, dl = dnext;
    int tn = (ts + 1 < CHK) ? ts + 1 : ts;
    vnext = vp[(size_t)tn * 3072];
    dnext = dp[(size_t)tn * 512];
    const float* e = ep + (size_t)ts * 512;
    p *= dl;
#pragma unroll
    for (int i = 0; i < 32; i++) {
      float ei = e[i];
      float kv = (1.f - ei) * vj;
      S[i] = ei * S[i] + kv;
    }
  }
  float* Tc = T + ((size_t)bh * NC + c) * 2048;
#pragma unroll
  for (int i = 0; i < 32; i++) Tc[i * 64 + lane] = S[i];
  if (lane < 32) P[((size_t)bh * NC + c) * 32 + lane] = p;
}

// ---------------- pass B: sequential cross-chunk state propagation ----------------
__global__ __launch_bounds__(256) void passB_k(const float* __restrict__ T,
                                               const float* __restrict__ P,
                                               float* __restrict__ Sg) {
  int bh = blockIdx.x;
  int tid = threadIdx.x;
  int f = tid * 8, i = f >> 6;
  float s[8];
#pragma unroll
  for (int e = 0; e < 8; e++) s[e] = 0.f;
  for (int c = 0; c < NC; c++) {
    size_t base = ((size_t)bh * NC + c) * 2048 + f;
    float pc = P[((size_t)bh * NC + c) * 32 + i];
#pragma unroll
    for (int e = 0; e < 8; e++) {
      Sg[base + e] = s[e];                 // state at chunk start
      s[e] = pc * s[e] + T[base + e];
    }
  }
}

// ---------------- pass C: chunk-local scan with injected start state ----------------
__global__ __launch_bounds__(256) void passC_k(const float* __restrict__ decay,
                                               const float* __restrict__ qkvg,
                                               const float* __restrict__ Sg,
                                               float* __restrict__ osc) {
  int wave = threadIdx.x >> 6, lane = threadIdx.x & 63;
  int c = blockIdx.x * 4 + wave, bh = blockIdx.y;
  int b = bh >> 4, h = bh & 15;
  size_t t0 = (size_t)b * Lseq + c * CHK;
  const float* ep = decay + t0 * 512 + h * 32;
  const float* qp = qkvg + t0 * 3072 + h * 32;
  const float* vp = qkvg + t0 * 3072 + 1024 + h * 64 + lane;
  float* op = osc + t0 * 1024 + h * 64 + lane;
  float S[32];
  const float* Sgc = Sg + ((size_t)bh * NC + c) * 2048;
#pragma unroll
  for (int i = 0; i < 32; i++) S[i] = Sgc[i * 64 + lane];
  float vnext = vp[0];
#pragma unroll 1
  for (int ts = 0; ts < CHK; ts++) {
    float vj = vnext;
    int tn = (ts + 1 < CHK) ? ts + 1 : ts;
    vnext = vp[(size_t)tn * 3072];
    const float* e = ep + (size_t)ts * 512;
    const float* q = qp + (size_t)ts * 3072;
    float a0 = 0.f, a1 = 0.f, a2 = 0.f, a3 = 0.f;
#pragma unroll
    for (int i = 0; i < 32; i += 4) {
      float e0 = e[i], e1 = e[i + 1], e2 = e[i + 2], e3 = e[i + 3];
      S[i + 0] = e0 * S[i + 0] + (1.f - e0) * vj; a0 += q[i + 0] * S[i + 0];
      S[i + 1] = e1 * S[i + 1] + (1.f - e1) * vj; a1 += q[i + 1] * S[i + 1];
      S[i + 2] = e2 * S[i + 2] + (1.f - e2) * vj; a2 += q[i + 2] * S[i + 2];
      S[i + 3] = e3 * S[i + 3] + (1.f - e3) * vj; a3 += q[i + 3] * S[i + 3];
    }
    op[(size_t)ts * 1024] = (a0 + a1) + (a2 + a3);
  }
}

// -------- post-scan: aug sigmoid term + groupnorm(64) + silu(g) gate -> bf16 --------
__global__ __launch_bounds__(256) void postscan_k(const float* __restrict__ osc,
                                                  const float* __restrict__ qkvg,
                                                  const float* __restrict__ decay,
                                                  const float* __restrict__ aug,
                                                  const float* __restrict__ gb,
                                                  u16* __restrict__ o2) {
  int m = blockIdx.x;
  int tid = threadIdx.x;
  int h = tid >> 4, t16 = tid & 15;
  int j0 = t16 * 4;
  size_t base = (size_t)m * 3072;
  float4 ov = *(const float4*)&osc[(size_t)m * 1024 + h * 64 + j0];
  int i0 = t16 * 2;
  float q0 = qkvg[base + h * 32 + i0], q1 = qkvg[base + h * 32 + i0 + 1];
  float kA = 1.f - decay[(size_t)m * 512 + h * 32 + i0];
  float kB = 1.f - decay[(size_t)m * 512 + h * 32 + i0 + 1];
  float aw = q0 * aug[h * 32 + i0] * kA + q1 * aug[h * 32 + i0 + 1] * kB;
  aw += __shfl_xor(aw, 1); aw += __shfl_xor(aw, 2);
  aw += __shfl_xor(aw, 4); aw += __shfl_xor(aw, 8);
  float4 vv = *(const float4*)&qkvg[base + 1024 + h * 64 + j0];
  ov.x += 1.f / (1.f + expf(-aw * vv.x));
  ov.y += 1.f / (1.f + expf(-aw * vv.y));
  ov.z += 1.f / (1.f + expf(-aw * vv.z));
  ov.w += 1.f / (1.f + expf(-aw * vv.w));
  float s = ov.x + ov.y + ov.z + ov.w;
  s += __shfl_xor(s, 1); s += __shfl_xor(s, 2);
  s += __shfl_xor(s, 4); s += __shfl_xor(s, 8);
  float mean = s * (1.f / 64.f);
  float d0 = ov.x - mean, d1 = ov.y - mean, d2 = ov.z - mean, d3 = ov.w - mean;
  float ss = d0 * d0 + d1 * d1 + d2 * d2 + d3 * d3;
  ss += __shfl_xor(ss, 1); ss += __shfl_xor(ss, 2);
  ss += __shfl_xor(ss, 4); ss += __shfl_xor(ss, 8);
  float rs = rsqrtf(ss * (1.f / 64.f) + 1e-5f);
  float4 gv = *(const float4*)&qkvg[base + 2048 + h * 64 + j0];
  float g0 = gv.x + gb[h * 64 + j0 + 0];
  float g1 = gv.y + gb[h * 64 + j0 + 1];
  float g2 = gv.z + gb[h * 64 + j0 + 2];
  float g3 = gv.w + gb[h * 64 + j0 + 3];
  ushort4 o;
  o.x = f2bf((g0 / (1.f + expf(-g0))) * d0 * rs);
  o.y = f2bf((g1 / (1.f + expf(-g1))) * d1 * rs);
  o.z = f2bf((g2 / (1.f + expf(-g2))) * d2 * rs);
  o.w = f2bf((g3 / (1.f + expf(-g3))) * d3 * rs);
  *(ushort4*)&o2[(size_t)m * 1024 + h * 64 + j0] = o;
}

// ---------------- bf16 MFMA GEMM: C(MxN) = A(MxK) * B(NxK)^T ----------------
// Staging: global_load_lds width=16 into unpadded 128x32 tiles (m97 pattern).
// EPI 0: Cf[row*N+col] = v
// EPI 1: Cf[(l*B+b)*D+col] = v + addsrc[same]   (row = b*L+l; transpose to (L,B,D))
// EPI 2: Cf[row*D+col] = v + addsrc[same]
// EPI 3: GLU: even col=u1, odd col=u2 -> Cbf[row*(N/2) + col/2] = bf16(silu(u1)*u2)
template <int EPI>
__global__ __launch_bounds__(256) void gemm_bt(const u16* __restrict__ A,
                                               const u16* __restrict__ B,
                                               int M, int N, int K,
                                               float* __restrict__ Cf,
                                               const float* __restrict__ addsrc,
                                               u16* __restrict__ Cbf) {
  __shared__ __align__(16) u16 lA[128 * 32];
  __shared__ __align__(16) u16 lB[128 * 32];
  const int tid = threadIdx.x;
  const int wave = tid >> 6, lane = tid & 63;
  const int m0 = blockIdx.y * 128, n0 = blockIdx.x * 128;
  const int wm = wave & 1, wn = wave >> 1;
  f32x4 acc[4][4];
#pragma unroll
  for (int a = 0; a < 4; a++)
#pragma unroll
    for (int b = 0; b < 4; b++) acc[a][b] = {0.f, 0.f, 0.f, 0.f};

  const int srow = lane >> 2;          // staging: instr j covers rows j*16..+16
  const int sk8 = (lane & 3) * 8;
  const int kofs = (lane >> 4) * 8;
  const int rsel = lane & 15;
  for (int k0 = 0; k0 < K; k0 += 32) {
    __syncthreads();
#pragma unroll
    for (int it = 0; it < 2; it++) {
      int j = wave * 2 + it;
      int row = j * 16 + srow;
      gll16(A + (size_t)(m0 + row) * K + k0 + sk8, &lA[j * 512]);
      gll16(B + (size_t)(n0 + row) * K + k0 + sk8, &lB[j * 512]);
    }
    __syncthreads();
    bf16x8 af[4], bfr[4];
#pragma unroll
    for (int t = 0; t < 4; t++) {
      af[t] = __builtin_bit_cast(bf16x8, *(const u16x8*)&lA[(wm * 64 + t * 16 + rsel) * 32 + kofs]);
      bfr[t] = __builtin_bit_cast(bf16x8, *(const u16x8*)&lB[(wn * 64 + t * 16 + rsel) * 32 + kofs]);
    }
#pragma unroll
    for (int tm = 0; tm < 4; tm++)
#pragma unroll
      for (int tn = 0; tn < 4; tn++)
        acc[tm][tn] = __builtin_amdgcn_mfma_f32_16x16x32_bf16(af[tm], bfr[tn], acc[tm][tn], 0, 0, 0);
  }

  const int rquad = (lane >> 4) * 4;
  const int csel = lane & 15;
#pragma unroll
  for (int tm = 0; tm < 4; tm++) {
    int rowb = m0 + wm * 64 + tm * 16 + rquad;
#pragma unroll
    for (int tn = 0; tn < 4; tn++) {
      int col = n0 + wn * 64 + tn * 16 + csel;
#pragma unroll
      for (int r = 0; r < 4; r++) {
        float v = acc[tm][tn][r];
        int row = rowb + r;
        if (EPI == 0) {
          Cf[(size_t)row * N + col] = v;
        } else if (EPI == 1) {
          int l = row & (Lseq - 1), bb = row >> 11;
          size_t o = ((size_t)(l * Bb + bb)) * Dd + col;
          Cf[o] = v + addsrc[o];
        } else if (EPI == 2) {
          size_t o = (size_t)row * Dd + col;
          Cf[o] = v + addsrc[o];
        } else {
          float partner = __shfl_xor(v, 1);
          if ((lane & 1) == 0) {
            float p = (v / (1.f + expf(-v))) * partner;
            Cbf[(size_t)row * (N >> 1) + (col >> 1)] = f2bf(p);
          }
        }
      }
    }
  }
}

extern "C" void kernel_launch(void* const* d_in, const int* in_sizes, int n_in,
                              void* d_out, int out_size, void* d_ws, size_t ws_size,
                              hipStream_t stream) {
  const float* x = (const float*)d_in[0];
  const float* tn_w = (const float*)d_in[1];
  const float* tn_b = (const float*)d_in[2];
  const float* conv_w = (const float*)d_in[3];
  const float* q_w = (const float*)d_in[4];
  const float* kg_w = (const float*)d_in[5];
  const float* v_w = (const float*)d_in[6];
  const float* g_w = (const float*)d_in[7];
  const float* g_b = (const float*)d_in[8];
  const float* out_w = (const float*)d_in[9];
  const float* aug = (const float*)d_in[10];
  const float* cn_w = (const float*)d_in[11];
  const float* cn_b = (const float*)d_in[12];
  const float* l1_w = (const float*)d_in[13];
  const float* l2_w = (const float*)d_in[14];
  const float* l3_w = (const float*)d_in[15];
  float* out = (float*)d_out;
  char* ws = (char*)d_ws;

  // workspace layout (<= 210.6 MB); regions reused across stage lifetimes
  u16* Wqkvg = (u16*)(ws + 0);                 // 6 MB   (3072 x 1024)
  u16* Wout = (u16*)(ws + 6291456);            // 2 MB
  u16* Wl12 = (u16*)(ws + 8388608);            // 11 MB  (5632 x 1024, interleaved)
  u16* Wl3 = (u16*)(ws + 19922944);            // 5.5 MB (1024 x 2816)
  float* hbuf = (float*)(ws + 25690112);       // 32 MB: h -> osc
  float* osc = hbuf;
  u16* ybf = (u16*)(ws + 59244544);            // 16 MB: ybf -> Sg -> o2bf
  float* Sg = (float*)(ws + 59244544);
  u16* o2bf = (u16*)(ws + 59244544);
  float* qkvg = (float*)(ws + 76021760);       // 96 MB: qkvg -> x1/zbf/pbf
  float* x1 = (float*)(ws + 76021760);
  u16* zbf = (u16*)(ws + 109576192);
  u16* pbf = (u16*)(ws + 126353408);
  float* decay = (float*)(ws + 176685056);     // 16 MB
  float* Tbuf = (float*)(ws + 193462272);      // 16 MB
  float* Pbuf = (float*)(ws + 210239488);      // 256 KB -> ends 210501632

  dim3 b256(256);
  // weight prep (transpose + bf16 cast); l1/l2 interleaved for fused GLU epilogue
  transpose_bf16<<<dim3(16, 32), b256, 0, stream>>>(q_w, Wqkvg, 1024, 512, 1, 0);
  transpose_bf16<<<dim3(16, 32), b256, 0, stream>>>(kg_w, Wqkvg + 512 * 1024, 1024, 512, 1, 0);
  transpose_bf16<<<dim3(32, 32), b256, 0, stream>>>(v_w, Wqkvg + 1024 * 1024, 1024, 1024, 1, 0);
  transpose_bf16<<<dim3(32, 32), b256, 0, stream>>>(g_w, Wqkvg + 2048 * 1024, 1024, 1024, 1, 0);
  transpose_bf16<<<dim3(32, 32), b256, 0, stream>>>(out_w, Wout, 1024, 1024, 1, 0);
  transpose_bf16<<<dim3(88, 32), b256, 0, stream>>>(l1_w, Wl12, 1024, 2816, 2, 0);
  transpose_bf16<<<dim3(88, 32), b256, 0, stream>>>(l2_w, Wl12, 1024, 2816, 2, 1);
  transpose_bf16<<<dim3(32, 88), b256, 0, stream>>>(l3_w, Wl3, 2816, 1024, 1, 0);

  ln1_k<<<8192, b256, 0, stream>>>(x, tn_w, tn_b, hbuf);
  conv_k<<<8192, b256, 0, stream>>>(hbuf, conv_w, ybf);
  gemm_bt<0><<<dim3(24, 64), b256, 0, stream>>>(ybf, Wqkvg, 8192, 3072, 1024, qkvg, nullptr, nullptr);
  gate_k<<<16384, b256, 0, stream>>>(qkvg, decay);
  passA_k<<<dim3(NC / 4, 64), b256, 0, stream>>>(decay, qkvg, Tbuf, Pbuf);
  passB_k<<<64, b256, 0, stream>>>(Tbuf, Pbuf, Sg);
  passC_k<<<dim3(NC / 4, 64), b256, 0, stream>>>(decay, qkvg, Sg, osc);
  postscan_k<<<8192, b256, 0, stream>>>(osc, qkvg, decay, aug, g_b, o2bf);
  gemm_bt<1><<<dim3(8, 64), b256, 0, stream>>>(o2bf, Wout, 8192, 1024, 1024, x1, x, nullptr);
  ln2_k<<<8192, b256, 0, stream>>>(x1, cn_w, cn_b, zbf);
  gemm_bt<3><<<dim3(44, 64), b256, 0, stream>>>(zbf, Wl12, 8192, 5632, 1024, nullptr, nullptr, pbf);
  gemm_bt<2><<<dim3(8, 64), b256, 0, stream>>>(pbf, Wl3, 8192, 1024, 2816, out, x1, nullptr);
}

// Round 3
// 732.010 us; speedup vs baseline: 1.7881x; 1.0322x over previous
//
#include <hip/hip_runtime.h>

// MetaLA decoder layer on gfx950.
// R3: (a) k-chunk rotation swizzle baked into ALL GEMM-operand global layouts
//     (weights via prep_k; activations via conv/ln2/postscan/EPI3) so LDS
//     fragment reads are bank-conflict-free; (b) gate fused into QKVG epilogue;
//     (c) Wl12 16-col interleave -> shfl-free GLU epilogue; (d) fused weight prep.

#define Lseq 2048
#define Bb 4
#define Dd 1024
#define Hh 16
#define GLUD 2816
#define NC 32
#define CHK 64

typedef float f32x4 __attribute__((ext_vector_type(4)));
typedef __bf16 bf16x8 __attribute__((ext_vector_type(8)));
typedef unsigned short u16;
typedef u16 u16x8 __attribute__((ext_vector_type(8)));

__device__ __forceinline__ u16 f2bf(float f) {
  unsigned int u = __float_as_uint(f);
  u += 0x7fffu + ((u >> 16) & 1u);
  return (u16)(u >> 16);
}

// swizzled column index: rotate 16B sub-chunks within each 32-elem k-group by (row>>1)
__device__ __forceinline__ int swz(int col, int row) {
  return (col & ~31) | ((((col >> 3) + (row >> 1)) & 3) << 3) | (col & 7);
}

__device__ __forceinline__ void gll16(const void* g, void* l) {
  __builtin_amdgcn_global_load_lds((const __attribute__((address_space(1))) void*)g,
                                   (__attribute__((address_space(3))) void*)l, 16, 0, 0);
}

__device__ __forceinline__ float block_sum(float v, float* red) {
#pragma unroll
  for (int o = 32; o > 0; o >>= 1) v += __shfl_down(v, o);
  __syncthreads();
  if ((threadIdx.x & 63) == 0) red[threadIdx.x >> 6] = v;
  __syncthreads();
  return red[0] + red[1] + red[2] + red[3];
}

// ---------------- LN1: x (L,B,D) -> h (B,L,D) fp32 ----------------
__global__ __launch_bounds__(256) void ln1_k(const float* __restrict__ x,
                                             const float* __restrict__ w,
                                             const float* __restrict__ bia,
                                             float* __restrict__ h) {
  __shared__ float red[4];
  int r = blockIdx.x;           // r = l*B + b
  int l = r >> 2, bb = r & 3;
  const float* xr = x + (size_t)r * Dd;
  int d0 = threadIdx.x * 4;
  float4 xv = *(const float4*)&xr[d0];
  float mean = block_sum(xv.x + xv.y + xv.z + xv.w, red) * (1.f / Dd);
  float a0 = xv.x - mean, a1 = xv.y - mean, a2 = xv.z - mean, a3 = xv.w - mean;
  float var = block_sum(a0 * a0 + a1 * a1 + a2 * a2 + a3 * a3, red) * (1.f / Dd);
  float rs = rsqrtf(var + 1e-5f);
  float4 ov;
  ov.x = a0 * rs * w[d0 + 0] + bia[d0 + 0];
  ov.y = a1 * rs * w[d0 + 1] + bia[d0 + 1];
  ov.z = a2 * rs * w[d0 + 2] + bia[d0 + 2];
  ov.w = a3 * rs * w[d0 + 3] + bia[d0 + 3];
  *(float4*)&h[((size_t)(bb * Lseq + l)) * Dd + d0] = ov;
}

// ---------------- LN2: x1 (row r) -> z bf16 swizzled ----------------
__global__ __launch_bounds__(256) void ln2_k(const float* __restrict__ x1,
                                             const float* __restrict__ w,
                                             const float* __restrict__ bia,
                                             u16* __restrict__ z) {
  __shared__ float red[4];
  int r = blockIdx.x;
  const float* xr = x1 + (size_t)r * Dd;
  int d0 = threadIdx.x * 4;
  float4 xv = *(const float4*)&xr[d0];
  float mean = block_sum(xv.x + xv.y + xv.z + xv.w, red) * (1.f / Dd);
  float a0 = xv.x - mean, a1 = xv.y - mean, a2 = xv.z - mean, a3 = xv.w - mean;
  float var = block_sum(a0 * a0 + a1 * a1 + a2 * a2 + a3 * a3, red) * (1.f / Dd);
  float rs = rsqrtf(var + 1e-5f);
  ushort4 o;
  o.x = f2bf(a0 * rs * w[d0 + 0] + bia[d0 + 0]);
  o.y = f2bf(a1 * rs * w[d0 + 1] + bia[d0 + 1]);
  o.z = f2bf(a2 * rs * w[d0 + 2] + bia[d0 + 2]);
  o.w = f2bf(a3 * rs * w[d0 + 3] + bia[d0 + 3]);
  int dcol = (d0 & ~31) | ((((d0 >> 3) + (r >> 1)) & 3) << 3) | (d0 & 7);
  *(ushort4*)&z[(size_t)r * Dd + dcol] = o;
}

// ------------- conv4 causal + SiLU -> y bf16 swizzled (B*L, D) -------------
__global__ __launch_bounds__(256) void conv_k(const float* __restrict__ h,
                                              const float* __restrict__ cw,
                                              u16* __restrict__ ybf) {
  int m = blockIdx.x;           // m = b*L + l
  int b = m >> 11, l = m & (Lseq - 1);
  int d0 = threadIdx.x * 4;
  float4 acc = {0.f, 0.f, 0.f, 0.f};
  const float* hb = h + ((size_t)b * Lseq) * Dd + d0;
#pragma unroll
  for (int w = 0; w < 4; w++) {
    int ll = l - 3 + w;
    if (ll >= 0) {
      float4 hv = *(const float4*)&hb[(size_t)ll * Dd];
      acc.x += hv.x * cw[(d0 + 0) * 4 + w];
      acc.y += hv.y * cw[(d0 + 1) * 4 + w];
      acc.z += hv.z * cw[(d0 + 2) * 4 + w];
      acc.w += hv.w * cw[(d0 + 3) * 4 + w];
    }
  }
  ushort4 o;
  o.x = f2bf(acc.x / (1.f + expf(-acc.x)));
  o.y = f2bf(acc.y / (1.f + expf(-acc.y)));
  o.z = f2bf(acc.z / (1.f + expf(-acc.z)));
  o.w = f2bf(acc.w / (1.f + expf(-acc.w)));
  int dcol = (d0 & ~31) | ((((d0 >> 3) + (m >> 1)) & 3) << 3) | (d0 & 7);
  *(ushort4*)&ybf[(size_t)m * Dd + dcol] = o;
}

// -------- fused weight prep: transpose + bf16 + swizzle (+Wl12 interleave) --------
__global__ __launch_bounds__(256) void prep_k(const float* __restrict__ q_w,
                                              const float* __restrict__ kg_w,
                                              const float* __restrict__ v_w,
                                              const float* __restrict__ g_w,
                                              const float* __restrict__ out_w,
                                              const float* __restrict__ l1_w,
                                              const float* __restrict__ l2_w,
                                              const float* __restrict__ l3_w,
                                              u16* __restrict__ Wqkvg,
                                              u16* __restrict__ Wout,
                                              u16* __restrict__ Wl12,
                                              u16* __restrict__ Wl3) {
  __shared__ float tile[32][33];
  int blk = blockIdx.x;
  const float* src;
  u16* dst;
  int R, C, ilv = 0, off = 0, base;
  if (blk < 512)       { src = q_w;   dst = Wqkvg;              R = 1024; C = 512;  base = 0; }
  else if (blk < 1024) { src = kg_w;  dst = Wqkvg + 512 * 1024; R = 1024; C = 512;  base = 512; }
  else if (blk < 2048) { src = v_w;   dst = Wqkvg + 1024 * 1024; R = 1024; C = 1024; base = 1024; }
  else if (blk < 3072) { src = g_w;   dst = Wqkvg + 2048 * 1024; R = 1024; C = 1024; base = 2048; }
  else if (blk < 4096) { src = out_w; dst = Wout;               R = 1024; C = 1024; base = 3072; }
  else if (blk < 6912) { src = l1_w;  dst = Wl12; R = 1024; C = 2816; ilv = 1; off = 0; base = 4096; }
  else if (blk < 9728) { src = l2_w;  dst = Wl12; R = 1024; C = 2816; ilv = 1; off = 1; base = 6912; }
  else                 { src = l3_w;  dst = Wl3;  R = 2816; C = 1024; base = 9728; }
  int local = blk - base;
  int ct = C >> 5;
  int bx = local % ct, by = local / ct;
  int tx = threadIdx.x & 31, ty = threadIdx.x >> 5;  // 32x8
  int c0 = bx * 32, r0 = by * 32;
#pragma unroll
  for (int k = 0; k < 4; k++)
    tile[ty + 8 * k][tx] = src[(size_t)(r0 + ty + 8 * k) * C + c0 + tx];
  __syncthreads();
#pragma unroll
  for (int k = 0; k < 4; k++) {
    int c = c0 + ty + 8 * k;
    int dstrow = ilv ? (((c >> 4) << 5) + off * 16 + (c & 15)) : c;
    int kpos = r0 + tx;
    dst[(size_t)dstrow * R + swz(kpos, dstrow)] = f2bf(tile[tx][ty + 8 * k]);
  }
}

// ---- pass A: per-chunk T (32x64) and decay product P (32); 4 waves = 4 chunks ----
__global__ __launch_bounds__(256) void passA_k(const float* __restrict__ decay,
                                               const float* __restrict__ qkvg,
                                               float* __restrict__ T,
                                               float* __restrict__ P) {
  int wave = threadIdx.x >> 6, lane = threadIdx.x & 63;
  int c = blockIdx.x * 4 + wave, bh = blockIdx.y;
  int b = bh >> 4, h = bh & 15;
  size_t t0 = (size_t)b * Lseq + c * CHK;        // first timestep row
  const float* ep = decay + t0 * 512 + h * 32;   // uniform base
  const float* vp = qkvg + t0 * 3072 + 1024 + h * 64 + lane;
  const float* dp = decay + t0 * 512 + h * 32 + (lane & 31);
  float S[32];
#pragma unroll
  for (int i = 0; i < 32; i++) S[i] = 0.f;
  float p = 1.f;
  float vnext = vp[0], dnext = dp[0];
#pragma unroll 1
  for (int ts = 0; ts < CHK; ts++) {
    float vj = vnext, dl = dnext;
    int tn = (ts + 1 < CHK) ? ts + 1 : ts;
    vnext = vp[(size_t)tn * 3072];
    dnext = dp[(size_t)tn * 512];
    const float* e = ep + (size_t)ts * 512;
    p *= dl;
#pragma unroll
    for (int i = 0; i < 32; i++) {
      float ei = e[i];
      float kv = (1.f - ei) * vj;
      S[i] = ei * S[i] + kv;
    }
  }
  float* Tc = T + ((size_t)bh * NC + c) * 2048;
#pragma unroll
  for (int i = 0; i < 32; i++) Tc[i * 64 + lane] = S[i];
  if (lane < 32) P[((size_t)bh * NC + c) * 32 + lane] = p;
}

// ---- pass B: sequential cross-chunk propagation (Sg may alias T; read-first) ----
__global__ __launch_bounds__(256) void passB_k(const float* __restrict__ T,
                                               const float* __restrict__ P,
                                               float* __restrict__ Sg) {
  int bh = blockIdx.x;
  int tid = threadIdx.x;
  int f = tid * 8, i = f >> 6;
  float s[8];
#pragma unroll
  for (int e = 0; e < 8; e++) s[e] = 0.f;
  for (int c = 0; c < NC; c++) {
    size_t base = ((size_t)bh * NC + c) * 2048 + f;
    float pc = P[((size_t)bh * NC + c) * 32 + i];
#pragma unroll
    for (int e = 0; e < 8; e++) {
      float tv = T[base + e];
      Sg[base + e] = s[e];                 // state at chunk start (aliases T[c])
      s[e] = pc * s[e] + tv;
    }
  }
}

// ---------------- pass C: chunk-local scan with injected start state ----------------
__global__ __launch_bounds__(256) void passC_k(const float* __restrict__ decay,
                                               const float* __restrict__ qkvg,
                                               const float* __restrict__ Sg,
                                               float* __restrict__ osc) {
  int wave = threadIdx.x >> 6, lane = threadIdx.x & 63;
  int c = blockIdx.x * 4 + wave, bh = blockIdx.y;
  int b = bh >> 4, h = bh & 15;
  size_t t0 = (size_t)b * Lseq + c * CHK;
  const float* ep = decay + t0 * 512 + h * 32;
  const float* qp = qkvg + t0 * 3072 + h * 32;
  const float* vp = qkvg + t0 * 3072 + 1024 + h * 64 + lane;
  float* op = osc + t0 * 1024 + h * 64 + lane;
  float S[32];
  const float* Sgc = Sg + ((size_t)bh * NC + c) * 2048;
#pragma unroll
  for (int i = 0; i < 32; i++) S[i] = Sgc[i * 64 + lane];
  float vnext = vp[0];
#pragma unroll 1
  for (int ts = 0; ts < CHK; ts++) {
    float vj = vnext;
    int tn = (ts + 1 < CHK) ? ts + 1 : ts;
    vnext = vp[(size_t)tn * 3072];
    const float* e = ep + (size_t)ts * 512;
    const float* q = qp + (size_t)ts * 3072;
    float a0 = 0.f, a1 = 0.f, a2 = 0.f, a3 = 0.f;
#pragma unroll
    for (int i = 0; i < 32; i += 4) {
      float e0 = e[i], e1 = e[i + 1], e2 = e[i + 2], e3 = e[i + 3];
      S[i + 0] = e0 * S[i + 0] + (1.f - e0) * vj; a0 += q[i + 0] * S[i + 0];
      S[i + 1] = e1 * S[i + 1] + (1.f - e1) * vj; a1 += q[i + 1] * S[i + 1];
      S[i + 2] = e2 * S[i + 2] + (1.f - e2) * vj; a2 += q[i + 2] * S[i + 2];
      S[i + 3] = e3 * S[i + 3] + (1.f - e3) * vj; a3 += q[i + 3] * S[i + 3];
    }
    op[(size_t)ts * 1024] = (a0 + a1) + (a2 + a3);
  }
}

// -------- post-scan: aug + groupnorm(64) + silu(g) gate -> bf16 swizzled --------
__global__ __launch_bounds__(256) void postscan_k(const float* __restrict__ osc,
                                                  const float* __restrict__ qkvg,
                                                  const float* __restrict__ decay,
                                                  const float* __restrict__ aug,
                                                  const float* __restrict__ gb,
                                                  u16* __restrict__ o2) {
  int m = blockIdx.x;
  int tid = threadIdx.x;
  int h = tid >> 4, t16 = tid & 15;
  int j0 = t16 * 4;
  size_t base = (size_t)m * 3072;
  float4 ov = *(const float4*)&osc[(size_t)m * 1024 + h * 64 + j0];
  int i0 = t16 * 2;
  float q0 = qkvg[base + h * 32 + i0], q1 = qkvg[base + h * 32 + i0 + 1];
  float kA = 1.f - decay[(size_t)m * 512 + h * 32 + i0];
  float kB = 1.f - decay[(size_t)m * 512 + h * 32 + i0 + 1];
  float aw = q0 * aug[h * 32 + i0] * kA + q1 * aug[h * 32 + i0 + 1] * kB;
  aw += __shfl_xor(aw, 1); aw += __shfl_xor(aw, 2);
  aw += __shfl_xor(aw, 4); aw += __shfl_xor(aw, 8);
  float4 vv = *(const float4*)&qkvg[base + 1024 + h * 64 + j0];
  ov.x += 1.f / (1.f + expf(-aw * vv.x));
  ov.y += 1.f / (1.f + expf(-aw * vv.y));
  ov.z += 1.f / (1.f + expf(-aw * vv.z));
  ov.w += 1.f / (1.f + expf(-aw * vv.w));
  float s = ov.x + ov.y + ov.z + ov.w;
  s += __shfl_xor(s, 1); s += __shfl_xor(s, 2);
  s += __shfl_xor(s, 4); s += __shfl_xor(s, 8);
  float mean = s * (1.f / 64.f);
  float d0 = ov.x - mean, d1 = ov.y - mean, d2 = ov.z - mean, d3 = ov.w - mean;
  float ss = d0 * d0 + d1 * d1 + d2 * d2 + d3 * d3;
  ss += __shfl_xor(ss, 1); ss += __shfl_xor(ss, 2);
  ss += __shfl_xor(ss, 4); ss += __shfl_xor(ss, 8);
  float rs = rsqrtf(ss * (1.f / 64.f) + 1e-5f);
  float4 gv = *(const float4*)&qkvg[base + 2048 + h * 64 + j0];
  float g0 = gv.x + gb[h * 64 + j0 + 0];
  float g1 = gv.y + gb[h * 64 + j0 + 1];
  float g2 = gv.z + gb[h * 64 + j0 + 2];
  float g3 = gv.w + gb[h * 64 + j0 + 3];
  ushort4 o;
  o.x = f2bf((g0 / (1.f + expf(-g0))) * d0 * rs);
  o.y = f2bf((g1 / (1.f + expf(-g1))) * d1 * rs);
  o.z = f2bf((g2 / (1.f + expf(-g2))) * d2 * rs);
  o.w = f2bf((g3 / (1.f + expf(-g3))) * d3 * rs);
  int col = h * 64 + j0;
  int dcol = (col & ~31) | ((((col >> 3) + (m >> 1)) & 3) << 3) | (col & 7);
  *(ushort4*)&o2[(size_t)m * 1024 + dcol] = o;
}

// ---------------- bf16 MFMA GEMM: C(MxN) = A(MxK) * B(NxK)^T ----------------
// A/B stored k-chunk-rotated (swz); staging via global_load_lds width=16.
// EPI 0: qkvg cols [512,1024) -> decay; else Cf[row*N+col] = v
// EPI 1: Cf[(l*B+b)*D+col] = v + addsrc[same]   (row = b*L+l)
// EPI 2: Cf[row*D+col] = v + addsrc[same]
// EPI 3: GLU, Wl12 16-interleaved: u1=acc[tm][2t], u2=acc[tm][2t+1] (same lane)
template <int EPI>
__global__ __launch_bounds__(256) void gemm_bt(const u16* __restrict__ A,
                                               const u16* __restrict__ B,
                                               int M, int N, int K,
                                               float* __restrict__ Cf,
                                               const float* __restrict__ addsrc,
                                               u16* __restrict__ Cbf,
                                               float* __restrict__ decayp) {
  __shared__ __align__(16) u16 lA[128 * 32];
  __shared__ __align__(16) u16 lB[128 * 32];
  const int tid = threadIdx.x;
  const int wave = tid >> 6, lane = tid & 63;
  const int m0 = blockIdx.y * 128, n0 = blockIdx.x * 128;
  const int wm = wave & 1, wn = wave >> 1;
  f32x4 acc[4][4];
#pragma unroll
  for (int a = 0; a < 4; a++)
#pragma unroll
    for (int b = 0; b < 4; b++) acc[a][b] = {0.f, 0.f, 0.f, 0.f};

  const int srow = lane >> 2;          // staging: instr j covers rows j*16..+16
  const int sk8 = (lane & 3) * 8;
  const int rsel = lane & 15;
  const int rot = (((lane >> 4) + (rsel >> 1)) & 3) << 3;  // swizzled k-chunk
  for (int k0 = 0; k0 < K; k0 += 32) {
    __syncthreads();
#pragma unroll
    for (int it = 0; it < 2; it++) {
      int j = wave * 2 + it;
      int row = j * 16 + srow;
      gll16(A + (size_t)(m0 + row) * K + k0 + sk8, &lA[j * 512]);
      gll16(B + (size_t)(n0 + row) * K + k0 + sk8, &lB[j * 512]);
    }
    __syncthreads();
    bf16x8 af[4], bfr[4];
#pragma unroll
    for (int t = 0; t < 4; t++) {
      af[t] = __builtin_bit_cast(bf16x8, *(const u16x8*)&lA[(wm * 64 + t * 16 + rsel) * 32 + rot]);
      bfr[t] = __builtin_bit_cast(bf16x8, *(const u16x8*)&lB[(wn * 64 + t * 16 + rsel) * 32 + rot]);
    }
#pragma unroll
    for (int tm = 0; tm < 4; tm++)
#pragma unroll
      for (int tn = 0; tn < 4; tn++)
        acc[tm][tn] = __builtin_amdgcn_mfma_f32_16x16x32_bf16(af[tm], bfr[tn], acc[tm][tn], 0, 0, 0);
  }

  const int rquad = (lane >> 4) * 4;
  const int csel = lane & 15;
#pragma unroll
  for (int tm = 0; tm < 4; tm++) {
    int rowb = m0 + wm * 64 + tm * 16 + rquad;
#pragma unroll
    for (int tn = 0; tn < 4; tn++) {
      int col = n0 + wn * 64 + tn * 16 + csel;
#pragma unroll
      for (int r = 0; r < 4; r++) {
        float v = acc[tm][tn][r];
        int row = rowb + r;
        if (EPI == 0) {
          if (col >= 512 && col < 1024) {
            float sg = 1.f / (1.f + expf(-v));
            decayp[(size_t)row * 512 + (col - 512)] = expf(0.0625f * logf(sg));
          } else {
            Cf[(size_t)row * N + col] = v;
          }
        } else if (EPI == 1) {
          int l = row & (Lseq - 1), bb = row >> 11;
          size_t o = ((size_t)(l * Bb + bb)) * Dd + col;
          Cf[o] = v + addsrc[o];
        } else if (EPI == 2) {
          size_t o = (size_t)row * Dd + col;
          Cf[o] = v + addsrc[o];
        } else {
          if ((tn & 1) == 0) {
            float u2 = acc[tm][tn + 1][r];
            float p = (v / (1.f + expf(-v))) * u2;
            int oc = (n0 >> 1) + wn * 32 + ((tn >> 1) << 4) + csel;
            Cbf[(size_t)row * (N >> 1) + swz(oc, row)] = f2bf(p);
          }
        }
      }
    }
  }
}

extern "C" void kernel_launch(void* const* d_in, const int* in_sizes, int n_in,
                              void* d_out, int out_size, void* d_ws, size_t ws_size,
                              hipStream_t stream) {
  const float* x = (const float*)d_in[0];
  const float* tn_w = (const float*)d_in[1];
  const float* tn_b = (const float*)d_in[2];
  const float* conv_w = (const float*)d_in[3];
  const float* q_w = (const float*)d_in[4];
  const float* kg_w = (const float*)d_in[5];
  const float* v_w = (const float*)d_in[6];
  const float* g_w = (const float*)d_in[7];
  const float* g_b = (const float*)d_in[8];
  const float* out_w = (const float*)d_in[9];
  const float* aug = (const float*)d_in[10];
  const float* cn_w = (const float*)d_in[11];
  const float* cn_b = (const float*)d_in[12];
  const float* l1_w = (const float*)d_in[13];
  const float* l2_w = (const float*)d_in[14];
  const float* l3_w = (const float*)d_in[15];
  float* out = (float*)d_out;
  char* ws = (char*)d_ws;

  // workspace layout (<= 210.6 MB); regions reused across stage lifetimes
  u16* Wqkvg = (u16*)(ws + 0);                 // 6 MB   (3072 x 1024)
  u16* Wout = (u16*)(ws + 6291456);            // 2 MB
  u16* Wl12 = (u16*)(ws + 8388608);            // 11 MB  (5632 x 1024, 16-interleaved)
  u16* Wl3 = (u16*)(ws + 19922944);            // 5.5 MB (1024 x 2816)
  float* hbuf = (float*)(ws + 25690112);       // 32 MB: h -> osc
  float* osc = hbuf;
  u16* ybf = (u16*)(ws + 59244544);            // 16 MB: ybf -> o2bf
  u16* o2bf = (u16*)(ws + 59244544);
  float* qkvg = (float*)(ws + 76021760);       // 96 MB: qkvg -> x1/zbf/pbf
  float* x1 = (float*)(ws + 76021760);
  u16* zbf = (u16*)(ws + 109576192);
  u16* pbf = (u16*)(ws + 126353408);
  float* decay = (float*)(ws + 176685056);     // 16 MB
  float* Tbuf = (float*)(ws + 193462272);      // 16 MB (Sg aliases; passB read-first)
  float* Sg = Tbuf;
  float* Pbuf = (float*)(ws + 210239488);      // 256 KB -> ends 210501632

  dim3 b256(256);
  prep_k<<<12544, b256, 0, stream>>>(q_w, kg_w, v_w, g_w, out_w, l1_w, l2_w, l3_w,
                                     Wqkvg, Wout, Wl12, Wl3);
  ln1_k<<<8192, b256, 0, stream>>>(x, tn_w, tn_b, hbuf);
  conv_k<<<8192, b256, 0, stream>>>(hbuf, conv_w, ybf);
  gemm_bt<0><<<dim3(24, 64), b256, 0, stream>>>(ybf, Wqkvg, 8192, 3072, 1024, qkvg, nullptr, nullptr, decay);
  passA_k<<<dim3(NC / 4, 64), b256, 0, stream>>>(decay, qkvg, Tbuf, Pbuf);
  passB_k<<<64, b256, 0, stream>>>(Tbuf, Pbuf, Sg);
  passC_k<<<dim3(NC / 4, 64), b256, 0, stream>>>(decay, qkvg, Sg, osc);
  postscan_k<<<8192, b256, 0, stream>>>(osc, qkvg, decay, aug, g_b, o2bf);
  gemm_bt<1><<<dim3(8, 64), b256, 0, stream>>>(o2bf, Wout, 8192, 1024, 1024, x1, x, nullptr, nullptr);
  ln2_k<<<8192, b256, 0, stream>>>(x1, cn_w, cn_b, zbf);
  gemm_bt<3><<<dim3(44, 64), b256, 0, stream>>>(zbf, Wl12, 8192, 5632, 1024, nullptr, nullptr, pbf, nullptr);
  gemm_bt<2><<<dim3(8, 64), b256, 0, stream>>>(pbf, Wl3, 8192, 1024, 2816, out, x1, nullptr, nullptr);
}

// Round 4
// 709.669 us; speedup vs baseline: 1.8444x; 1.0315x over previous
//
#include <hip/hip_runtime.h>

// MetaLA decoder layer on gfx950.
// R4: GEMM K-loop BK 32 -> 64 (32 KB LDS, double 32-k half-tiles): halves the
//     s_barrier vmcnt(0) drain count per FLOP, 8 gll16 in flight per wave.
//     Swizzled operand layouts (R3) unchanged; everything else unchanged.

#define Lseq 2048
#define Bb 4
#define Dd 1024
#define Hh 16
#define GLUD 2816
#define NC 32
#define CHK 64

typedef float f32x4 __attribute__((ext_vector_type(4)));
typedef __bf16 bf16x8 __attribute__((ext_vector_type(8)));
typedef unsigned short u16;
typedef u16 u16x8 __attribute__((ext_vector_type(8)));

__device__ __forceinline__ u16 f2bf(float f) {
  unsigned int u = __float_as_uint(f);
  u += 0x7fffu + ((u >> 16) & 1u);
  return (u16)(u >> 16);
}

// swizzled column index: rotate 16B sub-chunks within each 32-elem k-group by (row>>1)
__device__ __forceinline__ int swz(int col, int row) {
  return (col & ~31) | ((((col >> 3) + (row >> 1)) & 3) << 3) | (col & 7);
}

__device__ __forceinline__ void gll16(const void* g, void* l) {
  __builtin_amdgcn_global_load_lds((const __attribute__((address_space(1))) void*)g,
                                   (__attribute__((address_space(3))) void*)l, 16, 0, 0);
}

__device__ __forceinline__ float block_sum(float v, float* red) {
#pragma unroll
  for (int o = 32; o > 0; o >>= 1) v += __shfl_down(v, o);
  __syncthreads();
  if ((threadIdx.x & 63) == 0) red[threadIdx.x >> 6] = v;
  __syncthreads();
  return red[0] + red[1] + red[2] + red[3];
}

// ---------------- LN1: x (L,B,D) -> h (B,L,D) fp32 ----------------
__global__ __launch_bounds__(256) void ln1_k(const float* __restrict__ x,
                                             const float* __restrict__ w,
                                             const float* __restrict__ bia,
                                             float* __restrict__ h) {
  __shared__ float red[4];
  int r = blockIdx.x;           // r = l*B + b
  int l = r >> 2, bb = r & 3;
  const float* xr = x + (size_t)r * Dd;
  int d0 = threadIdx.x * 4;
  float4 xv = *(const float4*)&xr[d0];
  float mean = block_sum(xv.x + xv.y + xv.z + xv.w, red) * (1.f / Dd);
  float a0 = xv.x - mean, a1 = xv.y - mean, a2 = xv.z - mean, a3 = xv.w - mean;
  float var = block_sum(a0 * a0 + a1 * a1 + a2 * a2 + a3 * a3, red) * (1.f / Dd);
  float rs = rsqrtf(var + 1e-5f);
  float4 ov;
  ov.x = a0 * rs * w[d0 + 0] + bia[d0 + 0];
  ov.y = a1 * rs * w[d0 + 1] + bia[d0 + 1];
  ov.z = a2 * rs * w[d0 + 2] + bia[d0 + 2];
  ov.w = a3 * rs * w[d0 + 3] + bia[d0 + 3];
  *(float4*)&h[((size_t)(bb * Lseq + l)) * Dd + d0] = ov;
}

// ---------------- LN2: x1 (row r) -> z bf16 swizzled ----------------
__global__ __launch_bounds__(256) void ln2_k(const float* __restrict__ x1,
                                             const float* __restrict__ w,
                                             const float* __restrict__ bia,
                                             u16* __restrict__ z) {
  __shared__ float red[4];
  int r = blockIdx.x;
  const float* xr = x1 + (size_t)r * Dd;
  int d0 = threadIdx.x * 4;
  float4 xv = *(const float4*)&xr[d0];
  float mean = block_sum(xv.x + xv.y + xv.z + xv.w, red) * (1.f / Dd);
  float a0 = xv.x - mean, a1 = xv.y - mean, a2 = xv.z - mean, a3 = xv.w - mean;
  float var = block_sum(a0 * a0 + a1 * a1 + a2 * a2 + a3 * a3, red) * (1.f / Dd);
  float rs = rsqrtf(var + 1e-5f);
  ushort4 o;
  o.x = f2bf(a0 * rs * w[d0 + 0] + bia[d0 + 0]);
  o.y = f2bf(a1 * rs * w[d0 + 1] + bia[d0 + 1]);
  o.z = f2bf(a2 * rs * w[d0 + 2] + bia[d0 + 2]);
  o.w = f2bf(a3 * rs * w[d0 + 3] + bia[d0 + 3]);
  int dcol = (d0 & ~31) | ((((d0 >> 3) + (r >> 1)) & 3) << 3) | (d0 & 7);
  *(ushort4*)&z[(size_t)r * Dd + dcol] = o;
}

// ------------- conv4 causal + SiLU -> y bf16 swizzled (B*L, D) -------------
__global__ __launch_bounds__(256) void conv_k(const float* __restrict__ h,
                                              const float* __restrict__ cw,
                                              u16* __restrict__ ybf) {
  int m = blockIdx.x;           // m = b*L + l
  int b = m >> 11, l = m & (Lseq - 1);
  int d0 = threadIdx.x * 4;
  float4 acc = {0.f, 0.f, 0.f, 0.f};
  const float* hb = h + ((size_t)b * Lseq) * Dd + d0;
#pragma unroll
  for (int w = 0; w < 4; w++) {
    int ll = l - 3 + w;
    if (ll >= 0) {
      float4 hv = *(const float4*)&hb[(size_t)ll * Dd];
      acc.x += hv.x * cw[(d0 + 0) * 4 + w];
      acc.y += hv.y * cw[(d0 + 1) * 4 + w];
      acc.z += hv.z * cw[(d0 + 2) * 4 + w];
      acc.w += hv.w * cw[(d0 + 3) * 4 + w];
    }
  }
  ushort4 o;
  o.x = f2bf(acc.x / (1.f + expf(-acc.x)));
  o.y = f2bf(acc.y / (1.f + expf(-acc.y)));
  o.z = f2bf(acc.z / (1.f + expf(-acc.z)));
  o.w = f2bf(acc.w / (1.f + expf(-acc.w)));
  int dcol = (d0 & ~31) | ((((d0 >> 3) + (m >> 1)) & 3) << 3) | (d0 & 7);
  *(ushort4*)&ybf[(size_t)m * Dd + dcol] = o;
}

// -------- fused weight prep: transpose + bf16 + swizzle (+Wl12 interleave) --------
__global__ __launch_bounds__(256) void prep_k(const float* __restrict__ q_w,
                                              const float* __restrict__ kg_w,
                                              const float* __restrict__ v_w,
                                              const float* __restrict__ g_w,
                                              const float* __restrict__ out_w,
                                              const float* __restrict__ l1_w,
                                              const float* __restrict__ l2_w,
                                              const float* __restrict__ l3_w,
                                              u16* __restrict__ Wqkvg,
                                              u16* __restrict__ Wout,
                                              u16* __restrict__ Wl12,
                                              u16* __restrict__ Wl3) {
  __shared__ float tile[32][33];
  int blk = blockIdx.x;
  const float* src;
  u16* dst;
  int R, C, ilv = 0, off = 0, base;
  if (blk < 512)       { src = q_w;   dst = Wqkvg;              R = 1024; C = 512;  base = 0; }
  else if (blk < 1024) { src = kg_w;  dst = Wqkvg + 512 * 1024; R = 1024; C = 512;  base = 512; }
  else if (blk < 2048) { src = v_w;   dst = Wqkvg + 1024 * 1024; R = 1024; C = 1024; base = 1024; }
  else if (blk < 3072) { src = g_w;   dst = Wqkvg + 2048 * 1024; R = 1024; C = 1024; base = 2048; }
  else if (blk < 4096) { src = out_w; dst = Wout;               R = 1024; C = 1024; base = 3072; }
  else if (blk < 6912) { src = l1_w;  dst = Wl12; R = 1024; C = 2816; ilv = 1; off = 0; base = 4096; }
  else if (blk < 9728) { src = l2_w;  dst = Wl12; R = 1024; C = 2816; ilv = 1; off = 1; base = 6912; }
  else                 { src = l3_w;  dst = Wl3;  R = 2816; C = 1024; base = 9728; }
  int local = blk - base;
  int ct = C >> 5;
  int bx = local % ct, by = local / ct;
  int tx = threadIdx.x & 31, ty = threadIdx.x >> 5;  // 32x8
  int c0 = bx * 32, r0 = by * 32;
#pragma unroll
  for (int k = 0; k < 4; k++)
    tile[ty + 8 * k][tx] = src[(size_t)(r0 + ty + 8 * k) * C + c0 + tx];
  __syncthreads();
#pragma unroll
  for (int k = 0; k < 4; k++) {
    int c = c0 + ty + 8 * k;
    int dstrow = ilv ? (((c >> 4) << 5) + off * 16 + (c & 15)) : c;
    int kpos = r0 + tx;
    dst[(size_t)dstrow * R + swz(kpos, dstrow)] = f2bf(tile[tx][ty + 8 * k]);
  }
}

// ---- pass A: per-chunk T (32x64) and decay product P (32); 4 waves = 4 chunks ----
__global__ __launch_bounds__(256) void passA_k(const float* __restrict__ decay,
                                               const float* __restrict__ qkvg,
                                               float* __restrict__ T,
                                               float* __restrict__ P) {
  int wave = threadIdx.x >> 6, lane = threadIdx.x & 63;
  int c = blockIdx.x * 4 + wave, bh = blockIdx.y;
  int b = bh >> 4, h = bh & 15;
  size_t t0 = (size_t)b * Lseq + c * CHK;        // first timestep row
  const float* ep = decay + t0 * 512 + h * 32;   // uniform base
  const float* vp = qkvg + t0 * 3072 + 1024 + h * 64 + lane;
  const float* dp = decay + t0 * 512 + h * 32 + (lane & 31);
  float S[32];
#pragma unroll
  for (int i = 0; i < 32; i++) S[i] = 0.f;
  float p = 1.f;
  float vnext = vp[0], dnext = dp[0];
#pragma unroll 1
  for (int ts = 0; ts < CHK; ts++) {
    float vj = vnext, dl = dnext;
    int tn = (ts + 1 < CHK) ? ts + 1 : ts;
    vnext = vp[(size_t)tn * 3072];
    dnext = dp[(size_t)tn * 512];
    const float* e = ep + (size_t)ts * 512;
    p *= dl;
#pragma unroll
    for (int i = 0; i < 32; i++) {
      float ei = e[i];
      float kv = (1.f - ei) * vj;
      S[i] = ei * S[i] + kv;
    }
  }
  float* Tc = T + ((size_t)bh * NC + c) * 2048;
#pragma unroll
  for (int i = 0; i < 32; i++) Tc[i * 64 + lane] = S[i];
  if (lane < 32) P[((size_t)bh * NC + c) * 32 + lane] = p;
}

// ---- pass B: sequential cross-chunk propagation (Sg may alias T; read-first) ----
__global__ __launch_bounds__(256) void passB_k(const float* __restrict__ T,
                                               const float* __restrict__ P,
                                               float* __restrict__ Sg) {
  int bh = blockIdx.x;
  int tid = threadIdx.x;
  int f = tid * 8, i = f >> 6;
  float s[8];
#pragma unroll
  for (int e = 0; e < 8; e++) s[e] = 0.f;
  for (int c = 0; c < NC; c++) {
    size_t base = ((size_t)bh * NC + c) * 2048 + f;
    float pc = P[((size_t)bh * NC + c) * 32 + i];
#pragma unroll
    for (int e = 0; e < 8; e++) {
      float tv = T[base + e];
      Sg[base + e] = s[e];                 // state at chunk start (aliases T[c])
      s[e] = pc * s[e] + tv;
    }
  }
}

// ---------------- pass C: chunk-local scan with injected start state ----------------
__global__ __launch_bounds__(256) void passC_k(const float* __restrict__ decay,
                                               const float* __restrict__ qkvg,
                                               const float* __restrict__ Sg,
                                               float* __restrict__ osc) {
  int wave = threadIdx.x >> 6, lane = threadIdx.x & 63;
  int c = blockIdx.x * 4 + wave, bh = blockIdx.y;
  int b = bh >> 4, h = bh & 15;
  size_t t0 = (size_t)b * Lseq + c * CHK;
  const float* ep = decay + t0 * 512 + h * 32;
  const float* qp = qkvg + t0 * 3072 + h * 32;
  const float* vp = qkvg + t0 * 3072 + 1024 + h * 64 + lane;
  float* op = osc + t0 * 1024 + h * 64 + lane;
  float S[32];
  const float* Sgc = Sg + ((size_t)bh * NC + c) * 2048;
#pragma unroll
  for (int i = 0; i < 32; i++) S[i] = Sgc[i * 64 + lane];
  float vnext = vp[0];
#pragma unroll 1
  for (int ts = 0; ts < CHK; ts++) {
    float vj = vnext;
    int tn = (ts + 1 < CHK) ? ts + 1 : ts;
    vnext = vp[(size_t)tn * 3072];
    const float* e = ep + (size_t)ts * 512;
    const float* q = qp + (size_t)ts * 3072;
    float a0 = 0.f, a1 = 0.f, a2 = 0.f, a3 = 0.f;
#pragma unroll
    for (int i = 0; i < 32; i += 4) {
      float e0 = e[i], e1 = e[i + 1], e2 = e[i + 2], e3 = e[i + 3];
      S[i + 0] = e0 * S[i + 0] + (1.f - e0) * vj; a0 += q[i + 0] * S[i + 0];
      S[i + 1] = e1 * S[i + 1] + (1.f - e1) * vj; a1 += q[i + 1] * S[i + 1];
      S[i + 2] = e2 * S[i + 2] + (1.f - e2) * vj; a2 += q[i + 2] * S[i + 2];
      S[i + 3] = e3 * S[i + 3] + (1.f - e3) * vj; a3 += q[i + 3] * S[i + 3];
    }
    op[(size_t)ts * 1024] = (a0 + a1) + (a2 + a3);
  }
}

// -------- post-scan: aug + groupnorm(64) + silu(g) gate -> bf16 swizzled --------
__global__ __launch_bounds__(256) void postscan_k(const float* __restrict__ osc,
                                                  const float* __restrict__ qkvg,
                                                  const float* __restrict__ decay,
                                                  const float* __restrict__ aug,
                                                  const float* __restrict__ gb,
                                                  u16* __restrict__ o2) {
  int m = blockIdx.x;
  int tid = threadIdx.x;
  int h = tid >> 4, t16 = tid & 15;
  int j0 = t16 * 4;
  size_t base = (size_t)m * 3072;
  float4 ov = *(const float4*)&osc[(size_t)m * 1024 + h * 64 + j0];
  int i0 = t16 * 2;
  float q0 = qkvg[base + h * 32 + i0], q1 = qkvg[base + h * 32 + i0 + 1];
  float kA = 1.f - decay[(size_t)m * 512 + h * 32 + i0];
  float kB = 1.f - decay[(size_t)m * 512 + h * 32 + i0 + 1];
  float aw = q0 * aug[h * 32 + i0] * kA + q1 * aug[h * 32 + i0 + 1] * kB;
  aw += __shfl_xor(aw, 1); aw += __shfl_xor(aw, 2);
  aw += __shfl_xor(aw, 4); aw += __shfl_xor(aw, 8);
  float4 vv = *(const float4*)&qkvg[base + 1024 + h * 64 + j0];
  ov.x += 1.f / (1.f + expf(-aw * vv.x));
  ov.y += 1.f / (1.f + expf(-aw * vv.y));
  ov.z += 1.f / (1.f + expf(-aw * vv.z));
  ov.w += 1.f / (1.f + expf(-aw * vv.w));
  float s = ov.x + ov.y + ov.z + ov.w;
  s += __shfl_xor(s, 1); s += __shfl_xor(s, 2);
  s += __shfl_xor(s, 4); s += __shfl_xor(s, 8);
  float mean = s * (1.f / 64.f);
  float d0 = ov.x - mean, d1 = ov.y - mean, d2 = ov.z - mean, d3 = ov.w - mean;
  float ss = d0 * d0 + d1 * d1 + d2 * d2 + d3 * d3;
  ss += __shfl_xor(ss, 1); ss += __shfl_xor(ss, 2);
  ss += __shfl_xor(ss, 4); ss += __shfl_xor(ss, 8);
  float rs = rsqrtf(ss * (1.f / 64.f) + 1e-5f);
  float4 gv = *(const float4*)&qkvg[base + 2048 + h * 64 + j0];
  float g0 = gv.x + gb[h * 64 + j0 + 0];
  float g1 = gv.y + gb[h * 64 + j0 + 1];
  float g2 = gv.z + gb[h * 64 + j0 + 2];
  float g3 = gv.w + gb[h * 64 + j0 + 3];
  ushort4 o;
  o.x = f2bf((g0 / (1.f + expf(-g0))) * d0 * rs);
  o.y = f2bf((g1 / (1.f + expf(-g1))) * d1 * rs);
  o.z = f2bf((g2 / (1.f + expf(-g2))) * d2 * rs);
  o.w = f2bf((g3 / (1.f + expf(-g3))) * d3 * rs);
  int col = h * 64 + j0;
  int dcol = (col & ~31) | ((((col >> 3) + (m >> 1)) & 3) << 3) | (col & 7);
  *(ushort4*)&o2[(size_t)m * 1024 + dcol] = o;
}

// ---------------- bf16 MFMA GEMM: C(MxN) = A(MxK) * B(NxK)^T ----------------
// BK=64: two 128x32 half-tiles per buffer, one barrier pair per 64 k.
// A/B stored k-chunk-rotated (swz); staging via global_load_lds width=16.
// EPI 0: qkvg cols [512,1024) -> decay; else Cf[row*N+col] = v
// EPI 1: Cf[(l*B+b)*D+col] = v + addsrc[same]   (row = b*L+l)
// EPI 2: Cf[row*D+col] = v + addsrc[same]
// EPI 3: GLU, Wl12 16-interleaved: u1=acc[tm][2t], u2=acc[tm][2t+1] (same lane)
template <int EPI>
__global__ __launch_bounds__(256) void gemm_bt(const u16* __restrict__ A,
                                               const u16* __restrict__ B,
                                               int M, int N, int K,
                                               float* __restrict__ Cf,
                                               const float* __restrict__ addsrc,
                                               u16* __restrict__ Cbf,
                                               float* __restrict__ decayp) {
  __shared__ __align__(16) u16 lA[2 * 4096];   // [half g][128 rows][32 k]
  __shared__ __align__(16) u16 lB[2 * 4096];
  const int tid = threadIdx.x;
  const int wave = tid >> 6, lane = tid & 63;
  const int m0 = blockIdx.y * 128, n0 = blockIdx.x * 128;
  const int wm = wave & 1, wn = wave >> 1;
  f32x4 acc[4][4];
#pragma unroll
  for (int a = 0; a < 4; a++)
#pragma unroll
    for (int b = 0; b < 4; b++) acc[a][b] = {0.f, 0.f, 0.f, 0.f};

  const int srow = lane >> 2;          // staging: instr j covers rows j*16..+16
  const int sk8 = (lane & 3) * 8;
  const int rsel = lane & 15;
  const int rot = (((lane >> 4) + (rsel >> 1)) & 3) << 3;  // swizzled k-chunk
  for (int k0 = 0; k0 < K; k0 += 64) {
    __syncthreads();
#pragma unroll
    for (int g = 0; g < 2; g++) {
#pragma unroll
      for (int it = 0; it < 2; it++) {
        int j = wave * 2 + it;
        int row = j * 16 + srow;
        gll16(A + (size_t)(m0 + row) * K + k0 + g * 32 + sk8, &lA[g * 4096 + j * 512]);
        gll16(B + (size_t)(n0 + row) * K + k0 + g * 32 + sk8, &lB[g * 4096 + j * 512]);
      }
    }
    __syncthreads();
#pragma unroll
    for (int g = 0; g < 2; g++) {
      bf16x8 af[4], bfr[4];
#pragma unroll
      for (int t = 0; t < 4; t++) {
        af[t] = __builtin_bit_cast(bf16x8,
                 *(const u16x8*)&lA[g * 4096 + (wm * 64 + t * 16 + rsel) * 32 + rot]);
        bfr[t] = __builtin_bit_cast(bf16x8,
                 *(const u16x8*)&lB[g * 4096 + (wn * 64 + t * 16 + rsel) * 32 + rot]);
      }
#pragma unroll
      for (int tm = 0; tm < 4; tm++)
#pragma unroll
        for (int tn = 0; tn < 4; tn++)
          acc[tm][tn] = __builtin_amdgcn_mfma_f32_16x16x32_bf16(af[tm], bfr[tn], acc[tm][tn], 0, 0, 0);
    }
  }

  const int rquad = (lane >> 4) * 4;
  const int csel = lane & 15;
#pragma unroll
  for (int tm = 0; tm < 4; tm++) {
    int rowb = m0 + wm * 64 + tm * 16 + rquad;
#pragma unroll
    for (int tn = 0; tn < 4; tn++) {
      int col = n0 + wn * 64 + tn * 16 + csel;
#pragma unroll
      for (int r = 0; r < 4; r++) {
        float v = acc[tm][tn][r];
        int row = rowb + r;
        if (EPI == 0) {
          if (col >= 512 && col < 1024) {
            float sg = 1.f / (1.f + expf(-v));
            decayp[(size_t)row * 512 + (col - 512)] = expf(0.0625f * logf(sg));
          } else {
            Cf[(size_t)row * N + col] = v;
          }
        } else if (EPI == 1) {
          int l = row & (Lseq - 1), bb = row >> 11;
          size_t o = ((size_t)(l * Bb + bb)) * Dd + col;
          Cf[o] = v + addsrc[o];
        } else if (EPI == 2) {
          size_t o = (size_t)row * Dd + col;
          Cf[o] = v + addsrc[o];
        } else {
          if ((tn & 1) == 0) {
            float u2 = acc[tm][tn + 1][r];
            float p = (v / (1.f + expf(-v))) * u2;
            int oc = (n0 >> 1) + wn * 32 + ((tn >> 1) << 4) + csel;
            Cbf[(size_t)row * (N >> 1) + swz(oc, row)] = f2bf(p);
          }
        }
      }
    }
  }
}

extern "C" void kernel_launch(void* const* d_in, const int* in_sizes, int n_in,
                              void* d_out, int out_size, void* d_ws, size_t ws_size,
                              hipStream_t stream) {
  const float* x = (const float*)d_in[0];
  const float* tn_w = (const float*)d_in[1];
  const float* tn_b = (const float*)d_in[2];
  const float* conv_w = (const float*)d_in[3];
  const float* q_w = (const float*)d_in[4];
  const float* kg_w = (const float*)d_in[5];
  const float* v_w = (const float*)d_in[6];
  const float* g_w = (const float*)d_in[7];
  const float* g_b = (const float*)d_in[8];
  const float* out_w = (const float*)d_in[9];
  const float* aug = (const float*)d_in[10];
  const float* cn_w = (const float*)d_in[11];
  const float* cn_b = (const float*)d_in[12];
  const float* l1_w = (const float*)d_in[13];
  const float* l2_w = (const float*)d_in[14];
  const float* l3_w = (const float*)d_in[15];
  float* out = (float*)d_out;
  char* ws = (char*)d_ws;

  // workspace layout (<= 210.6 MB); regions reused across stage lifetimes
  u16* Wqkvg = (u16*)(ws + 0);                 // 6 MB   (3072 x 1024)
  u16* Wout = (u16*)(ws + 6291456);            // 2 MB
  u16* Wl12 = (u16*)(ws + 8388608);            // 11 MB  (5632 x 1024, 16-interleaved)
  u16* Wl3 = (u16*)(ws + 19922944);            // 5.5 MB (1024 x 2816)
  float* hbuf = (float*)(ws + 25690112);       // 32 MB: h -> osc
  float* osc = hbuf;
  u16* ybf = (u16*)(ws + 59244544);            // 16 MB: ybf -> o2bf
  u16* o2bf = (u16*)(ws + 59244544);
  float* qkvg = (float*)(ws + 76021760);       // 96 MB: qkvg -> x1/zbf/pbf
  float* x1 = (float*)(ws + 76021760);
  u16* zbf = (u16*)(ws + 109576192);
  u16* pbf = (u16*)(ws + 126353408);
  float* decay = (float*)(ws + 176685056);     // 16 MB
  float* Tbuf = (float*)(ws + 193462272);      // 16 MB (Sg aliases; passB read-first)
  float* Sg = Tbuf;
  float* Pbuf = (float*)(ws + 210239488);      // 256 KB -> ends 210501632

  dim3 b256(256);
  prep_k<<<12544, b256, 0, stream>>>(q_w, kg_w, v_w, g_w, out_w, l1_w, l2_w, l3_w,
                                     Wqkvg, Wout, Wl12, Wl3);
  ln1_k<<<8192, b256, 0, stream>>>(x, tn_w, tn_b, hbuf);
  conv_k<<<8192, b256, 0, stream>>>(hbuf, conv_w, ybf);
  gemm_bt<0><<<dim3(24, 64), b256, 0, stream>>>(ybf, Wqkvg, 8192, 3072, 1024, qkvg, nullptr, nullptr, decay);
  passA_k<<<dim3(NC / 4, 64), b256, 0, stream>>>(decay, qkvg, Tbuf, Pbuf);
  passB_k<<<64, b256, 0, stream>>>(Tbuf, Pbuf, Sg);
  passC_k<<<dim3(NC / 4, 64), b256, 0, stream>>>(decay, qkvg, Sg, osc);
  postscan_k<<<8192, b256, 0, stream>>>(osc, qkvg, decay, aug, g_b, o2bf);
  gemm_bt<1><<<dim3(8, 64), b256, 0, stream>>>(o2bf, Wout, 8192, 1024, 1024, x1, x, nullptr, nullptr);
  ln2_k<<<8192, b256, 0, stream>>>(x1, cn_w, cn_b, zbf);
  gemm_bt<3><<<dim3(44, 64), b256, 0, stream>>>(zbf, Wl12, 8192, 5632, 1024, nullptr, nullptr, pbf, nullptr);
  gemm_bt<2><<<dim3(8, 64), b256, 0, stream>>>(pbf, Wl3, 8192, 1024, 2816, out, x1, nullptr, nullptr);
}

// Round 5
// 697.709 us; speedup vs baseline: 1.8760x; 1.0171x over previous
//
#include <hip/hip_runtime.h>

// MetaLA decoder layer on gfx950.
// R5: (a) q/v/g stored bf16 by QKVG epilogue (decay stays fp32) -> scan read
//     traffic halved, GEMM write traffic -32 MB; (b) postscan fused into passC
//     (aug via uniform q/e already in registers, groupnorm via 64-lane shfl
//     allreduce, silu(g) gate, direct swizzled bf16 o2 store) -> kills the
//     postscan kernel and the 64 MB osc round-trip.

#define Lseq 2048
#define Bb 4
#define Dd 1024
#define Hh 16
#define GLUD 2816
#define NC 32
#define CHK 64

typedef float f32x4 __attribute__((ext_vector_type(4)));
typedef __bf16 bf16x8 __attribute__((ext_vector_type(8)));
typedef unsigned short u16;
typedef u16 u16x8 __attribute__((ext_vector_type(8)));

__device__ __forceinline__ u16 f2bf(float f) {
  unsigned int u = __float_as_uint(f);
  u += 0x7fffu + ((u >> 16) & 1u);
  return (u16)(u >> 16);
}
__device__ __forceinline__ float bf2f(u16 b) {
  return __uint_as_float(((unsigned int)b) << 16);
}

// swizzled column index: rotate 16B sub-chunks within each 32-elem k-group by (row>>1)
__device__ __forceinline__ int swz(int col, int row) {
  return (col & ~31) | ((((col >> 3) + (row >> 1)) & 3) << 3) | (col & 7);
}

__device__ __forceinline__ void gll16(const void* g, void* l) {
  __builtin_amdgcn_global_load_lds((const __attribute__((address_space(1))) void*)g,
                                   (__attribute__((address_space(3))) void*)l, 16, 0, 0);
}

__device__ __forceinline__ float block_sum(float v, float* red) {
#pragma unroll
  for (int o = 32; o > 0; o >>= 1) v += __shfl_down(v, o);
  __syncthreads();
  if ((threadIdx.x & 63) == 0) red[threadIdx.x >> 6] = v;
  __syncthreads();
  return red[0] + red[1] + red[2] + red[3];
}

// ---------------- LN1: x (L,B,D) -> h (B,L,D) fp32 ----------------
__global__ __launch_bounds__(256) void ln1_k(const float* __restrict__ x,
                                             const float* __restrict__ w,
                                             const float* __restrict__ bia,
                                             float* __restrict__ h) {
  __shared__ float red[4];
  int r = blockIdx.x;           // r = l*B + b
  int l = r >> 2, bb = r & 3;
  const float* xr = x + (size_t)r * Dd;
  int d0 = threadIdx.x * 4;
  float4 xv = *(const float4*)&xr[d0];
  float mean = block_sum(xv.x + xv.y + xv.z + xv.w, red) * (1.f / Dd);
  float a0 = xv.x - mean, a1 = xv.y - mean, a2 = xv.z - mean, a3 = xv.w - mean;
  float var = block_sum(a0 * a0 + a1 * a1 + a2 * a2 + a3 * a3, red) * (1.f / Dd);
  float rs = rsqrtf(var + 1e-5f);
  float4 ov;
  ov.x = a0 * rs * w[d0 + 0] + bia[d0 + 0];
  ov.y = a1 * rs * w[d0 + 1] + bia[d0 + 1];
  ov.z = a2 * rs * w[d0 + 2] + bia[d0 + 2];
  ov.w = a3 * rs * w[d0 + 3] + bia[d0 + 3];
  *(float4*)&h[((size_t)(bb * Lseq + l)) * Dd + d0] = ov;
}

// ---------------- LN2: x1 (row r) -> z bf16 swizzled ----------------
__global__ __launch_bounds__(256) void ln2_k(const float* __restrict__ x1,
                                             const float* __restrict__ w,
                                             const float* __restrict__ bia,
                                             u16* __restrict__ z) {
  __shared__ float red[4];
  int r = blockIdx.x;
  const float* xr = x1 + (size_t)r * Dd;
  int d0 = threadIdx.x * 4;
  float4 xv = *(const float4*)&xr[d0];
  float mean = block_sum(xv.x + xv.y + xv.z + xv.w, red) * (1.f / Dd);
  float a0 = xv.x - mean, a1 = xv.y - mean, a2 = xv.z - mean, a3 = xv.w - mean;
  float var = block_sum(a0 * a0 + a1 * a1 + a2 * a2 + a3 * a3, red) * (1.f / Dd);
  float rs = rsqrtf(var + 1e-5f);
  ushort4 o;
  o.x = f2bf(a0 * rs * w[d0 + 0] + bia[d0 + 0]);
  o.y = f2bf(a1 * rs * w[d0 + 1] + bia[d0 + 1]);
  o.z = f2bf(a2 * rs * w[d0 + 2] + bia[d0 + 2]);
  o.w = f2bf(a3 * rs * w[d0 + 3] + bia[d0 + 3]);
  int dcol = (d0 & ~31) | ((((d0 >> 3) + (r >> 1)) & 3) << 3) | (d0 & 7);
  *(ushort4*)&z[(size_t)r * Dd + dcol] = o;
}

// ------------- conv4 causal + SiLU -> y bf16 swizzled (B*L, D) -------------
__global__ __launch_bounds__(256) void conv_k(const float* __restrict__ h,
                                              const float* __restrict__ cw,
                                              u16* __restrict__ ybf) {
  int m = blockIdx.x;           // m = b*L + l
  int b = m >> 11, l = m & (Lseq - 1);
  int d0 = threadIdx.x * 4;
  float4 acc = {0.f, 0.f, 0.f, 0.f};
  const float* hb = h + ((size_t)b * Lseq) * Dd + d0;
#pragma unroll
  for (int w = 0; w < 4; w++) {
    int ll = l - 3 + w;
    if (ll >= 0) {
      float4 hv = *(const float4*)&hb[(size_t)ll * Dd];
      acc.x += hv.x * cw[(d0 + 0) * 4 + w];
      acc.y += hv.y * cw[(d0 + 1) * 4 + w];
      acc.z += hv.z * cw[(d0 + 2) * 4 + w];
      acc.w += hv.w * cw[(d0 + 3) * 4 + w];
    }
  }
  ushort4 o;
  o.x = f2bf(acc.x / (1.f + expf(-acc.x)));
  o.y = f2bf(acc.y / (1.f + expf(-acc.y)));
  o.z = f2bf(acc.z / (1.f + expf(-acc.z)));
  o.w = f2bf(acc.w / (1.f + expf(-acc.w)));
  int dcol = (d0 & ~31) | ((((d0 >> 3) + (m >> 1)) & 3) << 3) | (d0 & 7);
  *(ushort4*)&ybf[(size_t)m * Dd + dcol] = o;
}

// -------- fused weight prep: transpose + bf16 + swizzle (+Wl12 interleave) --------
__global__ __launch_bounds__(256) void prep_k(const float* __restrict__ q_w,
                                              const float* __restrict__ kg_w,
                                              const float* __restrict__ v_w,
                                              const float* __restrict__ g_w,
                                              const float* __restrict__ out_w,
                                              const float* __restrict__ l1_w,
                                              const float* __restrict__ l2_w,
                                              const float* __restrict__ l3_w,
                                              u16* __restrict__ Wqkvg,
                                              u16* __restrict__ Wout,
                                              u16* __restrict__ Wl12,
                                              u16* __restrict__ Wl3) {
  __shared__ float tile[32][33];
  int blk = blockIdx.x;
  const float* src;
  u16* dst;
  int R, C, ilv = 0, off = 0, base;
  if (blk < 512)       { src = q_w;   dst = Wqkvg;              R = 1024; C = 512;  base = 0; }
  else if (blk < 1024) { src = kg_w;  dst = Wqkvg + 512 * 1024; R = 1024; C = 512;  base = 512; }
  else if (blk < 2048) { src = v_w;   dst = Wqkvg + 1024 * 1024; R = 1024; C = 1024; base = 1024; }
  else if (blk < 3072) { src = g_w;   dst = Wqkvg + 2048 * 1024; R = 1024; C = 1024; base = 2048; }
  else if (blk < 4096) { src = out_w; dst = Wout;               R = 1024; C = 1024; base = 3072; }
  else if (blk < 6912) { src = l1_w;  dst = Wl12; R = 1024; C = 2816; ilv = 1; off = 0; base = 4096; }
  else if (blk < 9728) { src = l2_w;  dst = Wl12; R = 1024; C = 2816; ilv = 1; off = 1; base = 6912; }
  else                 { src = l3_w;  dst = Wl3;  R = 2816; C = 1024; base = 9728; }
  int local = blk - base;
  int ct = C >> 5;
  int bx = local % ct, by = local / ct;
  int tx = threadIdx.x & 31, ty = threadIdx.x >> 5;  // 32x8
  int c0 = bx * 32, r0 = by * 32;
#pragma unroll
  for (int k = 0; k < 4; k++)
    tile[ty + 8 * k][tx] = src[(size_t)(r0 + ty + 8 * k) * C + c0 + tx];
  __syncthreads();
#pragma unroll
  for (int k = 0; k < 4; k++) {
    int c = c0 + ty + 8 * k;
    int dstrow = ilv ? (((c >> 4) << 5) + off * 16 + (c & 15)) : c;
    int kpos = r0 + tx;
    dst[(size_t)dstrow * R + swz(kpos, dstrow)] = f2bf(tile[tx][ty + 8 * k]);
  }
}

// ---- pass A: per-chunk T (32x64) and decay product P (32); 4 waves = 4 chunks ----
__global__ __launch_bounds__(256) void passA_k(const float* __restrict__ decay,
                                               const u16* __restrict__ qkvg16,
                                               float* __restrict__ T,
                                               float* __restrict__ P) {
  int wave = threadIdx.x >> 6, lane = threadIdx.x & 63;
  int c = blockIdx.x * 4 + wave, bh = blockIdx.y;
  int b = bh >> 4, h = bh & 15;
  size_t t0 = (size_t)b * Lseq + c * CHK;        // first timestep row
  const float* ep = decay + t0 * 512 + h * 32;   // uniform base
  const u16* vp = qkvg16 + t0 * 3072 + 1024 + h * 64 + lane;
  const float* dp = decay + t0 * 512 + h * 32 + (lane & 31);
  float S[32];
#pragma unroll
  for (int i = 0; i < 32; i++) S[i] = 0.f;
  float p = 1.f;
  u16 vnext = vp[0];
  float dnext = dp[0];
#pragma unroll 1
  for (int ts = 0; ts < CHK; ts++) {
    float vj = bf2f(vnext), dl = dnext;
    int tn = (ts + 1 < CHK) ? ts + 1 : ts;
    vnext = vp[(size_t)tn * 3072];
    dnext = dp[(size_t)tn * 512];
    const float* e = ep + (size_t)ts * 512;
    p *= dl;
#pragma unroll
    for (int i = 0; i < 32; i++) {
      float ei = e[i];
      float kv = (1.f - ei) * vj;
      S[i] = ei * S[i] + kv;
    }
  }
  float* Tc = T + ((size_t)bh * NC + c) * 2048;
#pragma unroll
  for (int i = 0; i < 32; i++) Tc[i * 64 + lane] = S[i];
  if (lane < 32) P[((size_t)bh * NC + c) * 32 + lane] = p;
}

// ---- pass B: sequential cross-chunk propagation (Sg may alias T; read-first) ----
__global__ __launch_bounds__(256) void passB_k(const float* __restrict__ T,
                                               const float* __restrict__ P,
                                               float* __restrict__ Sg) {
  int bh = blockIdx.x;
  int tid = threadIdx.x;
  int f = tid * 8, i = f >> 6;
  float s[8];
#pragma unroll
  for (int e = 0; e < 8; e++) s[e] = 0.f;
  for (int c = 0; c < NC; c++) {
    size_t base = ((size_t)bh * NC + c) * 2048 + f;
    float pc = P[((size_t)bh * NC + c) * 32 + i];
#pragma unroll
    for (int e = 0; e < 8; e++) {
      float tv = T[base + e];
      Sg[base + e] = s[e];                 // state at chunk start (aliases T[c])
      s[e] = pc * s[e] + tv;
    }
  }
}

// ---- pass C fused: scan + aug sigmoid + groupnorm(64) + silu(g) -> o2 bf16 swz ----
// lane = j (head dim, 64). q/e uniform scalars; aug term computed redundantly
// per-lane from the same uniforms; groupnorm via 64-lane shfl_xor allreduce.
__global__ __launch_bounds__(256) void passC_k(const float* __restrict__ decay,
                                               const u16* __restrict__ qkvg16,
                                               const float* __restrict__ Sg,
                                               const float* __restrict__ aug,
                                               const float* __restrict__ gb,
                                               u16* __restrict__ o2) {
  int wave = threadIdx.x >> 6, lane = threadIdx.x & 63;
  int c = blockIdx.x * 4 + wave, bh = blockIdx.y;
  int b = bh >> 4, h = bh & 15;
  size_t t0 = (size_t)b * Lseq + c * CHK;
  const float* ep = decay + t0 * 512 + h * 32;
  const unsigned int* qp = (const unsigned int*)(qkvg16 + t0 * 3072 + h * 32);  // 16 u32/row
  const u16* vp = qkvg16 + t0 * 3072 + 1024 + h * 64 + lane;
  const u16* gp = qkvg16 + t0 * 3072 + 2048 + h * 64 + lane;
  float S[32];
  const float* Sgc = Sg + ((size_t)bh * NC + c) * 2048;
#pragma unroll
  for (int i = 0; i < 32; i++) S[i] = Sgc[i * 64 + lane];
  float vaug[32];
#pragma unroll
  for (int i = 0; i < 32; i++) vaug[i] = aug[h * 32 + i];
  float gbv = gb[h * 64 + lane];
  int colbase = h * 64 + lane;
  int colfix = (colbase & ~31) | (colbase & 7);
  int colrot0 = colbase >> 3;
  u16 vnext = vp[0], gnext = gp[0];
#pragma unroll 1
  for (int ts = 0; ts < CHK; ts++) {
    float vj = bf2f(vnext);
    float gg = bf2f(gnext) + gbv;
    int tn = (ts + 1 < CHK) ? ts + 1 : ts;
    vnext = vp[(size_t)tn * 3072];
    gnext = gp[(size_t)tn * 3072];
    const float* e = ep + (size_t)ts * 512;
    const unsigned int* q = qp + (size_t)ts * 1536;
    float a0 = 0.f, a1 = 0.f, aw = 0.f;
#pragma unroll
    for (int i = 0; i < 32; i += 2) {
      unsigned int qq = q[i >> 1];
      float q0 = __uint_as_float(qq << 16);
      float q1 = __uint_as_float(qq & 0xffff0000u);
      float e0 = e[i], e1 = e[i + 1];
      float k0 = 1.f - e0, k1 = 1.f - e1;
      S[i + 0] = e0 * S[i + 0] + k0 * vj; a0 += q0 * S[i + 0];
      S[i + 1] = e1 * S[i + 1] + k1 * vj; a1 += q1 * S[i + 1];
      aw += q0 * vaug[i] * k0 + q1 * vaug[i + 1] * k1;
    }
    float o = (a0 + a1) + 1.f / (1.f + expf(-aw * vj));
    // groupnorm over the 64 lanes (head dim)
    float s = o;
#pragma unroll
    for (int d = 1; d < 64; d <<= 1) s += __shfl_xor(s, d);
    float dcen = o - s * (1.f / 64.f);
    float ss = dcen * dcen;
#pragma unroll
    for (int d = 1; d < 64; d <<= 1) ss += __shfl_xor(ss, d);
    float rs = rsqrtf(ss * (1.f / 64.f) + 1e-5f);
    float res = (gg / (1.f + expf(-gg))) * dcen * rs;
    int m = (int)t0 + ts;
    int dcol = colfix | (((colrot0 + (m >> 1)) & 3) << 3);
    o2[(size_t)m * 1024 + dcol] = f2bf(res);
  }
}

// ---------------- bf16 MFMA GEMM: C(MxN) = A(MxK) * B(NxK)^T ----------------
// BK=64: two 128x32 half-tiles per buffer, one barrier pair per 64 k.
// A/B stored k-chunk-rotated (swz); staging via global_load_lds width=16.
// EPI 0: cols [512,1024) -> decay fp32; else Cbf[row*N+col] = bf16(v)  (q/v/g)
// EPI 1: Cf[(l*B+b)*D+col] = v + addsrc[same]   (row = b*L+l)
// EPI 2: Cf[row*D+col] = v + addsrc[same]
// EPI 3: GLU, Wl12 16-interleaved: u1=acc[tm][2t], u2=acc[tm][2t+1] (same lane)
template <int EPI>
__global__ __launch_bounds__(256) void gemm_bt(const u16* __restrict__ A,
                                               const u16* __restrict__ B,
                                               int M, int N, int K,
                                               float* __restrict__ Cf,
                                               const float* __restrict__ addsrc,
                                               u16* __restrict__ Cbf,
                                               float* __restrict__ decayp) {
  __shared__ __align__(16) u16 lA[2 * 4096];   // [half g][128 rows][32 k]
  __shared__ __align__(16) u16 lB[2 * 4096];
  const int tid = threadIdx.x;
  const int wave = tid >> 6, lane = tid & 63;
  const int m0 = blockIdx.y * 128, n0 = blockIdx.x * 128;
  const int wm = wave & 1, wn = wave >> 1;
  f32x4 acc[4][4];
#pragma unroll
  for (int a = 0; a < 4; a++)
#pragma unroll
    for (int b = 0; b < 4; b++) acc[a][b] = {0.f, 0.f, 0.f, 0.f};

  const int srow = lane >> 2;          // staging: instr j covers rows j*16..+16
  const int sk8 = (lane & 3) * 8;
  const int rsel = lane & 15;
  const int rot = (((lane >> 4) + (rsel >> 1)) & 3) << 3;  // swizzled k-chunk
  for (int k0 = 0; k0 < K; k0 += 64) {
    __syncthreads();
#pragma unroll
    for (int g = 0; g < 2; g++) {
#pragma unroll
      for (int it = 0; it < 2; it++) {
        int j = wave * 2 + it;
        int row = j * 16 + srow;
        gll16(A + (size_t)(m0 + row) * K + k0 + g * 32 + sk8, &lA[g * 4096 + j * 512]);
        gll16(B + (size_t)(n0 + row) * K + k0 + g * 32 + sk8, &lB[g * 4096 + j * 512]);
      }
    }
    __syncthreads();
#pragma unroll
    for (int g = 0; g < 2; g++) {
      bf16x8 af[4], bfr[4];
#pragma unroll
      for (int t = 0; t < 4; t++) {
        af[t] = __builtin_bit_cast(bf16x8,
                 *(const u16x8*)&lA[g * 4096 + (wm * 64 + t * 16 + rsel) * 32 + rot]);
        bfr[t] = __builtin_bit_cast(bf16x8,
                 *(const u16x8*)&lB[g * 4096 + (wn * 64 + t * 16 + rsel) * 32 + rot]);
      }
#pragma unroll
      for (int tm = 0; tm < 4; tm++)
#pragma unroll
        for (int tn = 0; tn < 4; tn++)
          acc[tm][tn] = __builtin_amdgcn_mfma_f32_16x16x32_bf16(af[tm], bfr[tn], acc[tm][tn], 0, 0, 0);
    }
  }

  const int rquad = (lane >> 4) * 4;
  const int csel = lane & 15;
#pragma unroll
  for (int tm = 0; tm < 4; tm++) {
    int rowb = m0 + wm * 64 + tm * 16 + rquad;
#pragma unroll
    for (int tn = 0; tn < 4; tn++) {
      int col = n0 + wn * 64 + tn * 16 + csel;
#pragma unroll
      for (int r = 0; r < 4; r++) {
        float v = acc[tm][tn][r];
        int row = rowb + r;
        if (EPI == 0) {
          if (col >= 512 && col < 1024) {
            float sg = 1.f / (1.f + expf(-v));
            decayp[(size_t)row * 512 + (col - 512)] = expf(0.0625f * logf(sg));
          } else {
            Cbf[(size_t)row * N + col] = f2bf(v);
          }
        } else if (EPI == 1) {
          int l = row & (Lseq - 1), bb = row >> 11;
          size_t o = ((size_t)(l * Bb + bb)) * Dd + col;
          Cf[o] = v + addsrc[o];
        } else if (EPI == 2) {
          size_t o = (size_t)row * Dd + col;
          Cf[o] = v + addsrc[o];
        } else {
          if ((tn & 1) == 0) {
            float u2 = acc[tm][tn + 1][r];
            float p = (v / (1.f + expf(-v))) * u2;
            int oc = (n0 >> 1) + wn * 32 + ((tn >> 1) << 4) + csel;
            Cbf[(size_t)row * (N >> 1) + swz(oc, row)] = f2bf(p);
          }
        }
      }
    }
  }
}

extern "C" void kernel_launch(void* const* d_in, const int* in_sizes, int n_in,
                              void* d_out, int out_size, void* d_ws, size_t ws_size,
                              hipStream_t stream) {
  const float* x = (const float*)d_in[0];
  const float* tn_w = (const float*)d_in[1];
  const float* tn_b = (const float*)d_in[2];
  const float* conv_w = (const float*)d_in[3];
  const float* q_w = (const float*)d_in[4];
  const float* kg_w = (const float*)d_in[5];
  const float* v_w = (const float*)d_in[6];
  const float* g_w = (const float*)d_in[7];
  const float* g_b = (const float*)d_in[8];
  const float* out_w = (const float*)d_in[9];
  const float* aug = (const float*)d_in[10];
  const float* cn_w = (const float*)d_in[11];
  const float* cn_b = (const float*)d_in[12];
  const float* l1_w = (const float*)d_in[13];
  const float* l2_w = (const float*)d_in[14];
  const float* l3_w = (const float*)d_in[15];
  float* out = (float*)d_out;
  char* ws = (char*)d_ws;

  // workspace layout (<= 206.4 MB); regions reused across stage lifetimes
  u16* Wqkvg = (u16*)(ws + 0);                 // 6 MB   (3072 x 1024)
  u16* Wout = (u16*)(ws + 6291456);            // 2 MB
  u16* Wl12 = (u16*)(ws + 8388608);            // 11 MB  (5632 x 1024, 16-interleaved)
  u16* Wl3 = (u16*)(ws + 19922944);            // 5.5 MB (1024 x 2816)
  float* hbuf = (float*)(ws + 25690112);       // 32 MB: h -> x1
  float* x1 = hbuf;
  u16* ybf = (u16*)(ws + 59244544);            // 16 MB: ybf -> o2bf
  u16* o2bf = (u16*)(ws + 59244544);
  u16* qkvg16 = (u16*)(ws + 76021760);         // 48 MB bf16 q/v/g -> zbf after scan
  u16* zbf = (u16*)(ws + 76021760);
  u16* pbf = (u16*)(ws + 126353408);           // 46.1 MB
  float* decay = (float*)(ws + 172490752);     // 16 MB fp32
  float* Tbuf = (float*)(ws + 189267968);      // 16 MB (Sg aliases; passB read-first)
  float* Sg = Tbuf;
  float* Pbuf = (float*)(ws + 206045184);      // 256 KB -> ends 206307328

  dim3 b256(256);
  prep_k<<<12544, b256, 0, stream>>>(q_w, kg_w, v_w, g_w, out_w, l1_w, l2_w, l3_w,
                                     Wqkvg, Wout, Wl12, Wl3);
  ln1_k<<<8192, b256, 0, stream>>>(x, tn_w, tn_b, hbuf);
  conv_k<<<8192, b256, 0, stream>>>(hbuf, conv_w, ybf);
  gemm_bt<0><<<dim3(24, 64), b256, 0, stream>>>(ybf, Wqkvg, 8192, 3072, 1024, nullptr, nullptr, qkvg16, decay);
  passA_k<<<dim3(NC / 4, 64), b256, 0, stream>>>(decay, qkvg16, Tbuf, Pbuf);
  passB_k<<<64, b256, 0, stream>>>(Tbuf, Pbuf, Sg);
  passC_k<<<dim3(NC / 4, 64), b256, 0, stream>>>(decay, qkvg16, Sg, aug, g_b, o2bf);
  gemm_bt<1><<<dim3(8, 64), b256, 0, stream>>>(o2bf, Wout, 8192, 1024, 1024, x1, x, nullptr, nullptr);
  ln2_k<<<8192, b256, 0, stream>>>(x1, cn_w, cn_b, zbf);
  gemm_bt<3><<<dim3(44, 64), b256, 0, stream>>>(zbf, Wl12, 8192, 5632, 1024, nullptr, nullptr, pbf, nullptr);
  gemm_bt<2><<<dim3(8, 64), b256, 0, stream>>>(pbf, Wl3, 8192, 1024, 2816, out, x1, nullptr, nullptr);
}

// Round 6
// 694.962 us; speedup vs baseline: 1.8834x; 1.0040x over previous
//
#include <hip/hip_runtime.h>

// MetaLA decoder layer on gfx950.
// R6: (a) scan wave index via readfirstlane -> e/q pointer chains provably
//     wave-uniform -> s_load (scalar) instead of divergent vector broadcasts;
//     (b) out & l3 GEMMs retiled 128x64 (24 KB LDS, grid 1024 = 4 blocks/CU);
//     (c) ln1 -> bf16 h (conv reads 4x); (d) passB grid 64 -> 512 blocks.

#define Lseq 2048
#define Bb 4
#define Dd 1024
#define Hh 16
#define GLUD 2816
#define NC 32
#define CHK 64

typedef float f32x4 __attribute__((ext_vector_type(4)));
typedef __bf16 bf16x8 __attribute__((ext_vector_type(8)));
typedef unsigned short u16;
typedef u16 u16x8 __attribute__((ext_vector_type(8)));

__device__ __forceinline__ u16 f2bf(float f) {
  unsigned int u = __float_as_uint(f);
  u += 0x7fffu + ((u >> 16) & 1u);
  return (u16)(u >> 16);
}
__device__ __forceinline__ float bf2f(u16 b) {
  return __uint_as_float(((unsigned int)b) << 16);
}

// swizzled column index: rotate 16B sub-chunks within each 32-elem k-group by (row>>1)
__device__ __forceinline__ int swz(int col, int row) {
  return (col & ~31) | ((((col >> 3) + (row >> 1)) & 3) << 3) | (col & 7);
}

__device__ __forceinline__ void gll16(const void* g, void* l) {
  __builtin_amdgcn_global_load_lds((const __attribute__((address_space(1))) void*)g,
                                   (__attribute__((address_space(3))) void*)l, 16, 0, 0);
}

__device__ __forceinline__ float block_sum(float v, float* red) {
#pragma unroll
  for (int o = 32; o > 0; o >>= 1) v += __shfl_down(v, o);
  __syncthreads();
  if ((threadIdx.x & 63) == 0) red[threadIdx.x >> 6] = v;
  __syncthreads();
  return red[0] + red[1] + red[2] + red[3];
}

// ---------------- LN1: x (L,B,D) -> h (B,L,D) bf16 ----------------
__global__ __launch_bounds__(256) void ln1_k(const float* __restrict__ x,
                                             const float* __restrict__ w,
                                             const float* __restrict__ bia,
                                             u16* __restrict__ h) {
  __shared__ float red[4];
  int r = blockIdx.x;           // r = l*B + b
  int l = r >> 2, bb = r & 3;
  const float* xr = x + (size_t)r * Dd;
  int d0 = threadIdx.x * 4;
  float4 xv = *(const float4*)&xr[d0];
  float mean = block_sum(xv.x + xv.y + xv.z + xv.w, red) * (1.f / Dd);
  float a0 = xv.x - mean, a1 = xv.y - mean, a2 = xv.z - mean, a3 = xv.w - mean;
  float var = block_sum(a0 * a0 + a1 * a1 + a2 * a2 + a3 * a3, red) * (1.f / Dd);
  float rs = rsqrtf(var + 1e-5f);
  ushort4 ov;
  ov.x = f2bf(a0 * rs * w[d0 + 0] + bia[d0 + 0]);
  ov.y = f2bf(a1 * rs * w[d0 + 1] + bia[d0 + 1]);
  ov.z = f2bf(a2 * rs * w[d0 + 2] + bia[d0 + 2]);
  ov.w = f2bf(a3 * rs * w[d0 + 3] + bia[d0 + 3]);
  *(ushort4*)&h[((size_t)(bb * Lseq + l)) * Dd + d0] = ov;
}

// ---------------- LN2: x1 (row r) -> z bf16 swizzled ----------------
__global__ __launch_bounds__(256) void ln2_k(const float* __restrict__ x1,
                                             const float* __restrict__ w,
                                             const float* __restrict__ bia,
                                             u16* __restrict__ z) {
  __shared__ float red[4];
  int r = blockIdx.x;
  const float* xr = x1 + (size_t)r * Dd;
  int d0 = threadIdx.x * 4;
  float4 xv = *(const float4*)&xr[d0];
  float mean = block_sum(xv.x + xv.y + xv.z + xv.w, red) * (1.f / Dd);
  float a0 = xv.x - mean, a1 = xv.y - mean, a2 = xv.z - mean, a3 = xv.w - mean;
  float var = block_sum(a0 * a0 + a1 * a1 + a2 * a2 + a3 * a3, red) * (1.f / Dd);
  float rs = rsqrtf(var + 1e-5f);
  ushort4 o;
  o.x = f2bf(a0 * rs * w[d0 + 0] + bia[d0 + 0]);
  o.y = f2bf(a1 * rs * w[d0 + 1] + bia[d0 + 1]);
  o.z = f2bf(a2 * rs * w[d0 + 2] + bia[d0 + 2]);
  o.w = f2bf(a3 * rs * w[d0 + 3] + bia[d0 + 3]);
  int dcol = (d0 & ~31) | ((((d0 >> 3) + (r >> 1)) & 3) << 3) | (d0 & 7);
  *(ushort4*)&z[(size_t)r * Dd + dcol] = o;
}

// ------------- conv4 causal + SiLU: h bf16 -> y bf16 swizzled (B*L, D) -------------
__global__ __launch_bounds__(256) void conv_k(const u16* __restrict__ h,
                                              const float* __restrict__ cw,
                                              u16* __restrict__ ybf) {
  int m = blockIdx.x;           // m = b*L + l
  int b = m >> 11, l = m & (Lseq - 1);
  int d0 = threadIdx.x * 4;
  float4 acc = {0.f, 0.f, 0.f, 0.f};
  const u16* hb = h + ((size_t)b * Lseq) * Dd + d0;
#pragma unroll
  for (int w = 0; w < 4; w++) {
    int ll = l - 3 + w;
    if (ll >= 0) {
      ushort4 hv = *(const ushort4*)&hb[(size_t)ll * Dd];
      acc.x += bf2f(hv.x) * cw[(d0 + 0) * 4 + w];
      acc.y += bf2f(hv.y) * cw[(d0 + 1) * 4 + w];
      acc.z += bf2f(hv.z) * cw[(d0 + 2) * 4 + w];
      acc.w += bf2f(hv.w) * cw[(d0 + 3) * 4 + w];
    }
  }
  ushort4 o;
  o.x = f2bf(acc.x / (1.f + expf(-acc.x)));
  o.y = f2bf(acc.y / (1.f + expf(-acc.y)));
  o.z = f2bf(acc.z / (1.f + expf(-acc.z)));
  o.w = f2bf(acc.w / (1.f + expf(-acc.w)));
  int dcol = (d0 & ~31) | ((((d0 >> 3) + (m >> 1)) & 3) << 3) | (d0 & 7);
  *(ushort4*)&ybf[(size_t)m * Dd + dcol] = o;
}

// -------- fused weight prep: transpose + bf16 + swizzle (+Wl12 interleave) --------
__global__ __launch_bounds__(256) void prep_k(const float* __restrict__ q_w,
                                              const float* __restrict__ kg_w,
                                              const float* __restrict__ v_w,
                                              const float* __restrict__ g_w,
                                              const float* __restrict__ out_w,
                                              const float* __restrict__ l1_w,
                                              const float* __restrict__ l2_w,
                                              const float* __restrict__ l3_w,
                                              u16* __restrict__ Wqkvg,
                                              u16* __restrict__ Wout,
                                              u16* __restrict__ Wl12,
                                              u16* __restrict__ Wl3) {
  __shared__ float tile[32][33];
  int blk = blockIdx.x;
  const float* src;
  u16* dst;
  int R, C, ilv = 0, off = 0, base;
  if (blk < 512)       { src = q_w;   dst = Wqkvg;              R = 1024; C = 512;  base = 0; }
  else if (blk < 1024) { src = kg_w;  dst = Wqkvg + 512 * 1024; R = 1024; C = 512;  base = 512; }
  else if (blk < 2048) { src = v_w;   dst = Wqkvg + 1024 * 1024; R = 1024; C = 1024; base = 1024; }
  else if (blk < 3072) { src = g_w;   dst = Wqkvg + 2048 * 1024; R = 1024; C = 1024; base = 2048; }
  else if (blk < 4096) { src = out_w; dst = Wout;               R = 1024; C = 1024; base = 3072; }
  else if (blk < 6912) { src = l1_w;  dst = Wl12; R = 1024; C = 2816; ilv = 1; off = 0; base = 4096; }
  else if (blk < 9728) { src = l2_w;  dst = Wl12; R = 1024; C = 2816; ilv = 1; off = 1; base = 6912; }
  else                 { src = l3_w;  dst = Wl3;  R = 2816; C = 1024; base = 9728; }
  int local = blk - base;
  int ct = C >> 5;
  int bx = local % ct, by = local / ct;
  int tx = threadIdx.x & 31, ty = threadIdx.x >> 5;  // 32x8
  int c0 = bx * 32, r0 = by * 32;
#pragma unroll
  for (int k = 0; k < 4; k++)
    tile[ty + 8 * k][tx] = src[(size_t)(r0 + ty + 8 * k) * C + c0 + tx];
  __syncthreads();
#pragma unroll
  for (int k = 0; k < 4; k++) {
    int c = c0 + ty + 8 * k;
    int dstrow = ilv ? (((c >> 4) << 5) + off * 16 + (c & 15)) : c;
    int kpos = r0 + tx;
    dst[(size_t)dstrow * R + swz(kpos, dstrow)] = f2bf(tile[tx][ty + 8 * k]);
  }
}

// ---- pass A: per-chunk T (32x64) and decay product P (32); 4 waves = 4 chunks ----
__global__ __launch_bounds__(256) void passA_k(const float* __restrict__ decay,
                                               const u16* __restrict__ qkvg16,
                                               float* __restrict__ T,
                                               float* __restrict__ P) {
  int wave = __builtin_amdgcn_readfirstlane((int)(threadIdx.x >> 6));
  int lane = threadIdx.x & 63;
  int c = blockIdx.x * 4 + wave, bh = blockIdx.y;
  int b = bh >> 4, h = bh & 15;
  size_t t0 = (size_t)b * Lseq + c * CHK;        // first timestep row
  const float* ep = decay + t0 * 512 + h * 32;   // wave-uniform base -> s_load
  const u16* vp = qkvg16 + t0 * 3072 + 1024 + h * 64 + lane;
  const float* dp = decay + t0 * 512 + h * 32 + (lane & 31);
  float S[32];
#pragma unroll
  for (int i = 0; i < 32; i++) S[i] = 0.f;
  float p = 1.f;
  u16 vnext = vp[0];
  float dnext = dp[0];
#pragma unroll 1
  for (int ts = 0; ts < CHK; ts++) {
    float vj = bf2f(vnext), dl = dnext;
    int tn = (ts + 1 < CHK) ? ts + 1 : ts;
    vnext = vp[(size_t)tn * 3072];
    dnext = dp[(size_t)tn * 512];
    const float* e = ep + (size_t)ts * 512;
    p *= dl;
#pragma unroll
    for (int i = 0; i < 32; i++) {
      float ei = e[i];
      float kv = (1.f - ei) * vj;
      S[i] = ei * S[i] + kv;
    }
  }
  float* Tc = T + ((size_t)bh * NC + c) * 2048;
#pragma unroll
  for (int i = 0; i < 32; i++) Tc[i * 64 + lane] = S[i];
  if (lane < 32) P[((size_t)bh * NC + c) * 32 + lane] = p;
}

// ---- pass B: sequential cross-chunk propagation (Sg aliases T; read-first) ----
__global__ __launch_bounds__(256) void passB_k(const float* __restrict__ T,
                                               const float* __restrict__ P,
                                               float* __restrict__ Sg) {
  int bh = blockIdx.x >> 3;
  int f = (blockIdx.x & 7) * 256 + threadIdx.x;  // 0..2047
  int i = f >> 6;
  float s = 0.f;
  for (int c = 0; c < NC; c++) {
    size_t base = ((size_t)bh * NC + c) * 2048 + f;
    float pc = P[((size_t)bh * NC + c) * 32 + i];
    float tv = T[base];
    Sg[base] = s;                        // state at chunk start (aliases T[c])
    s = pc * s + tv;
  }
}

// ---- pass C fused: scan + aug sigmoid + groupnorm(64) + silu(g) -> o2 bf16 swz ----
__global__ __launch_bounds__(256) void passC_k(const float* __restrict__ decay,
                                               const u16* __restrict__ qkvg16,
                                               const float* __restrict__ Sg,
                                               const float* __restrict__ aug,
                                               const float* __restrict__ gb,
                                               u16* __restrict__ o2) {
  int wave = __builtin_amdgcn_readfirstlane((int)(threadIdx.x >> 6));
  int lane = threadIdx.x & 63;
  int c = blockIdx.x * 4 + wave, bh = blockIdx.y;
  int b = bh >> 4, h = bh & 15;
  size_t t0 = (size_t)b * Lseq + c * CHK;
  const float* ep = decay + t0 * 512 + h * 32;                                  // uniform
  const unsigned int* qp = (const unsigned int*)(qkvg16 + t0 * 3072 + h * 32);  // uniform
  const u16* vp = qkvg16 + t0 * 3072 + 1024 + h * 64 + lane;
  const u16* gp = qkvg16 + t0 * 3072 + 2048 + h * 64 + lane;
  float S[32];
  const float* Sgc = Sg + ((size_t)bh * NC + c) * 2048;
#pragma unroll
  for (int i = 0; i < 32; i++) S[i] = Sgc[i * 64 + lane];
  float vaug[32];
#pragma unroll
  for (int i = 0; i < 32; i++) vaug[i] = aug[h * 32 + i];
  float gbv = gb[h * 64 + lane];
  int colbase = h * 64 + lane;
  int colfix = (colbase & ~31) | (colbase & 7);
  int colrot0 = colbase >> 3;
  u16 vnext = vp[0], gnext = gp[0];
#pragma unroll 1
  for (int ts = 0; ts < CHK; ts++) {
    float vj = bf2f(vnext);
    float gg = bf2f(gnext) + gbv;
    int tn = (ts + 1 < CHK) ? ts + 1 : ts;
    vnext = vp[(size_t)tn * 3072];
    gnext = gp[(size_t)tn * 3072];
    const float* e = ep + (size_t)ts * 512;
    const unsigned int* q = qp + (size_t)ts * 1536;
    float a0 = 0.f, a1 = 0.f, aw = 0.f;
#pragma unroll
    for (int i = 0; i < 32; i += 2) {
      unsigned int qq = q[i >> 1];
      float q0 = __uint_as_float(qq << 16);
      float q1 = __uint_as_float(qq & 0xffff0000u);
      float e0 = e[i], e1 = e[i + 1];
      float k0 = 1.f - e0, k1 = 1.f - e1;
      S[i + 0] = e0 * S[i + 0] + k0 * vj; a0 += q0 * S[i + 0];
      S[i + 1] = e1 * S[i + 1] + k1 * vj; a1 += q1 * S[i + 1];
      aw += q0 * vaug[i] * k0 + q1 * vaug[i + 1] * k1;
    }
    float o = (a0 + a1) + 1.f / (1.f + expf(-aw * vj));
    // groupnorm over the 64 lanes (head dim)
    float s = o;
#pragma unroll
    for (int d = 1; d < 64; d <<= 1) s += __shfl_xor(s, d);
    float dcen = o - s * (1.f / 64.f);
    float ss = dcen * dcen;
#pragma unroll
    for (int d = 1; d < 64; d <<= 1) ss += __shfl_xor(ss, d);
    float rs = rsqrtf(ss * (1.f / 64.f) + 1e-5f);
    float res = (gg / (1.f + expf(-gg))) * dcen * rs;
    int m = (int)t0 + ts;
    int dcol = colfix | (((colrot0 + (m >> 1)) & 3) << 3);
    o2[(size_t)m * 1024 + dcol] = f2bf(res);
  }
}

// ---------------- bf16 MFMA GEMM 128x128: C(MxN) = A(MxK) * B(NxK)^T ----------------
// EPI 0: cols [512,1024) -> decay fp32; else Cbf[row*N+col] = bf16(v)  (q/v/g)
// EPI 3: GLU, Wl12 16-interleaved: u1=acc[tm][2t], u2=acc[tm][2t+1] (same lane)
template <int EPI>
__global__ __launch_bounds__(256) void gemm_bt(const u16* __restrict__ A,
                                               const u16* __restrict__ B,
                                               int M, int N, int K,
                                               float* __restrict__ Cf,
                                               const float* __restrict__ addsrc,
                                               u16* __restrict__ Cbf,
                                               float* __restrict__ decayp) {
  __shared__ __align__(16) u16 lA[2 * 4096];   // [half g][128 rows][32 k]
  __shared__ __align__(16) u16 lB[2 * 4096];
  const int tid = threadIdx.x;
  const int wave = tid >> 6, lane = tid & 63;
  const int m0 = blockIdx.y * 128, n0 = blockIdx.x * 128;
  const int wm = wave & 1, wn = wave >> 1;
  f32x4 acc[4][4];
#pragma unroll
  for (int a = 0; a < 4; a++)
#pragma unroll
    for (int b = 0; b < 4; b++) acc[a][b] = {0.f, 0.f, 0.f, 0.f};

  const int srow = lane >> 2;          // staging: instr j covers rows j*16..+16
  const int sk8 = (lane & 3) * 8;
  const int rsel = lane & 15;
  const int rot = (((lane >> 4) + (rsel >> 1)) & 3) << 3;  // swizzled k-chunk
  for (int k0 = 0; k0 < K; k0 += 64) {
    __syncthreads();
#pragma unroll
    for (int g = 0; g < 2; g++) {
#pragma unroll
      for (int it = 0; it < 2; it++) {
        int j = wave * 2 + it;
        int row = j * 16 + srow;
        gll16(A + (size_t)(m0 + row) * K + k0 + g * 32 + sk8, &lA[g * 4096 + j * 512]);
        gll16(B + (size_t)(n0 + row) * K + k0 + g * 32 + sk8, &lB[g * 4096 + j * 512]);
      }
    }
    __syncthreads();
#pragma unroll
    for (int g = 0; g < 2; g++) {
      bf16x8 af[4], bfr[4];
#pragma unroll
      for (int t = 0; t < 4; t++) {
        af[t] = __builtin_bit_cast(bf16x8,
                 *(const u16x8*)&lA[g * 4096 + (wm * 64 + t * 16 + rsel) * 32 + rot]);
        bfr[t] = __builtin_bit_cast(bf16x8,
                 *(const u16x8*)&lB[g * 4096 + (wn * 64 + t * 16 + rsel) * 32 + rot]);
      }
#pragma unroll
      for (int tm = 0; tm < 4; tm++)
#pragma unroll
        for (int tn = 0; tn < 4; tn++)
          acc[tm][tn] = __builtin_amdgcn_mfma_f32_16x16x32_bf16(af[tm], bfr[tn], acc[tm][tn], 0, 0, 0);
    }
  }

  const int rquad = (lane >> 4) * 4;
  const int csel = lane & 15;
#pragma unroll
  for (int tm = 0; tm < 4; tm++) {
    int rowb = m0 + wm * 64 + tm * 16 + rquad;
#pragma unroll
    for (int tn = 0; tn < 4; tn++) {
      int col = n0 + wn * 64 + tn * 16 + csel;
#pragma unroll
      for (int r = 0; r < 4; r++) {
        float v = acc[tm][tn][r];
        int row = rowb + r;
        if (EPI == 0) {
          if (col >= 512 && col < 1024) {
            float sg = 1.f / (1.f + expf(-v));
            decayp[(size_t)row * 512 + (col - 512)] = expf(0.0625f * logf(sg));
          } else {
            Cbf[(size_t)row * N + col] = f2bf(v);
          }
        } else {
          if ((tn & 1) == 0) {
            float u2 = acc[tm][tn + 1][r];
            float p = (v / (1.f + expf(-v))) * u2;
            int oc = (n0 >> 1) + wn * 32 + ((tn >> 1) << 4) + csel;
            Cbf[(size_t)row * (N >> 1) + swz(oc, row)] = f2bf(p);
          }
        }
      }
    }
  }
}

// ---------------- bf16 MFMA GEMM 128x64 (4 blocks/CU for small-N GEMMs) ----------------
// EPI 1: Cf[(l*B+b)*D+col] = v + addsrc[same]   (row = b*L+l)
// EPI 2: Cf[row*D+col] = v + addsrc[same]
template <int EPI>
__global__ __launch_bounds__(256) void gemm_bt64(const u16* __restrict__ A,
                                                 const u16* __restrict__ B,
                                                 int M, int N, int K,
                                                 float* __restrict__ Cf,
                                                 const float* __restrict__ addsrc) {
  __shared__ __align__(16) u16 lA[2 * 4096];   // [half][128 rows][32 k]
  __shared__ __align__(16) u16 lB[2 * 2048];   // [half][64 rows][32 k]
  const int tid = threadIdx.x;
  const int wave = tid >> 6, lane = tid & 63;
  const int m0 = blockIdx.y * 128, n0 = blockIdx.x * 64;
  const int wm = wave & 1, wn = wave >> 1;     // 2x2: 64 rows x 32 cols per wave
  f32x4 acc[4][2];
#pragma unroll
  for (int a = 0; a < 4; a++)
#pragma unroll
    for (int b = 0; b < 2; b++) acc[a][b] = {0.f, 0.f, 0.f, 0.f};

  const int srow = lane >> 2;
  const int sk8 = (lane & 3) * 8;
  const int rsel = lane & 15;
  const int rot = (((lane >> 4) + (rsel >> 1)) & 3) << 3;
  for (int k0 = 0; k0 < K; k0 += 64) {
    __syncthreads();
#pragma unroll
    for (int g = 0; g < 2; g++) {
#pragma unroll
      for (int it = 0; it < 2; it++) {       // A: 8 instrs over 4 waves
        int j = wave * 2 + it;
        int row = j * 16 + srow;
        gll16(A + (size_t)(m0 + row) * K + k0 + g * 32 + sk8, &lA[g * 4096 + j * 512]);
      }
      {                                      // B: 4 instrs over 4 waves
        int row = wave * 16 + srow;
        gll16(B + (size_t)(n0 + row) * K + k0 + g * 32 + sk8, &lB[g * 2048 + wave * 512]);
      }
    }
    __syncthreads();
#pragma unroll
    for (int g = 0; g < 2; g++) {
      bf16x8 af[4], bfr[2];
#pragma unroll
      for (int t = 0; t < 4; t++)
        af[t] = __builtin_bit_cast(bf16x8,
                 *(const u16x8*)&lA[g * 4096 + (wm * 64 + t * 16 + rsel) * 32 + rot]);
#pragma unroll
      for (int t = 0; t < 2; t++)
        bfr[t] = __builtin_bit_cast(bf16x8,
                 *(const u16x8*)&lB[g * 2048 + (wn * 32 + t * 16 + rsel) * 32 + rot]);
#pragma unroll
      for (int tm = 0; tm < 4; tm++)
#pragma unroll
        for (int tn = 0; tn < 2; tn++)
          acc[tm][tn] = __builtin_amdgcn_mfma_f32_16x16x32_bf16(af[tm], bfr[tn], acc[tm][tn], 0, 0, 0);
    }
  }

  const int rquad = (lane >> 4) * 4;
  const int csel = lane & 15;
#pragma unroll
  for (int tm = 0; tm < 4; tm++) {
    int rowb = m0 + wm * 64 + tm * 16 + rquad;
#pragma unroll
    for (int tn = 0; tn < 2; tn++) {
      int col = n0 + wn * 32 + tn * 16 + csel;
#pragma unroll
      for (int r = 0; r < 4; r++) {
        float v = acc[tm][tn][r];
        int row = rowb + r;
        if (EPI == 1) {
          int l = row & (Lseq - 1), bb = row >> 11;
          size_t o = ((size_t)(l * Bb + bb)) * Dd + col;
          Cf[o] = v + addsrc[o];
        } else {
          size_t o = (size_t)row * Dd + col;
          Cf[o] = v + addsrc[o];
        }
      }
    }
  }
}

extern "C" void kernel_launch(void* const* d_in, const int* in_sizes, int n_in,
                              void* d_out, int out_size, void* d_ws, size_t ws_size,
                              hipStream_t stream) {
  const float* x = (const float*)d_in[0];
  const float* tn_w = (const float*)d_in[1];
  const float* tn_b = (const float*)d_in[2];
  const float* conv_w = (const float*)d_in[3];
  const float* q_w = (const float*)d_in[4];
  const float* kg_w = (const float*)d_in[5];
  const float* v_w = (const float*)d_in[6];
  const float* g_w = (const float*)d_in[7];
  const float* g_b = (const float*)d_in[8];
  const float* out_w = (const float*)d_in[9];
  const float* aug = (const float*)d_in[10];
  const float* cn_w = (const float*)d_in[11];
  const float* cn_b = (const float*)d_in[12];
  const float* l1_w = (const float*)d_in[13];
  const float* l2_w = (const float*)d_in[14];
  const float* l3_w = (const float*)d_in[15];
  float* out = (float*)d_out;
  char* ws = (char*)d_ws;

  // workspace layout (<= 206.4 MB); regions reused across stage lifetimes
  u16* Wqkvg = (u16*)(ws + 0);                 // 6 MB   (3072 x 1024)
  u16* Wout = (u16*)(ws + 6291456);            // 2 MB
  u16* Wl12 = (u16*)(ws + 8388608);            // 11 MB  (5632 x 1024, 16-interleaved)
  u16* Wl3 = (u16*)(ws + 19922944);            // 5.5 MB (1024 x 2816)
  u16* hbuf = (u16*)(ws + 25690112);           // 32 MB region: h bf16 -> x1 fp32
  float* x1 = (float*)(ws + 25690112);
  u16* ybf = (u16*)(ws + 59244544);            // 16 MB: ybf -> o2bf
  u16* o2bf = (u16*)(ws + 59244544);
  u16* qkvg16 = (u16*)(ws + 76021760);         // 48 MB bf16 q/v/g -> zbf after scan
  u16* zbf = (u16*)(ws + 76021760);
  u16* pbf = (u16*)(ws + 126353408);           // 46.1 MB
  float* decay = (float*)(ws + 172490752);     // 16 MB fp32
  float* Tbuf = (float*)(ws + 189267968);      // 16 MB (Sg aliases; passB read-first)
  float* Sg = Tbuf;
  float* Pbuf = (float*)(ws + 206045184);      // 256 KB -> ends 206307328

  dim3 b256(256);
  prep_k<<<12544, b256, 0, stream>>>(q_w, kg_w, v_w, g_w, out_w, l1_w, l2_w, l3_w,
                                     Wqkvg, Wout, Wl12, Wl3);
  ln1_k<<<8192, b256, 0, stream>>>(x, tn_w, tn_b, hbuf);
  conv_k<<<8192, b256, 0, stream>>>(hbuf, conv_w, ybf);
  gemm_bt<0><<<dim3(24, 64), b256, 0, stream>>>(ybf, Wqkvg, 8192, 3072, 1024, nullptr, nullptr, qkvg16, decay);
  passA_k<<<dim3(NC / 4, 64), b256, 0, stream>>>(decay, qkvg16, Tbuf, Pbuf);
  passB_k<<<512, b256, 0, stream>>>(Tbuf, Pbuf, Sg);
  passC_k<<<dim3(NC / 4, 64), b256, 0, stream>>>(decay, qkvg16, Sg, aug, g_b, o2bf);
  gemm_bt64<1><<<dim3(16, 64), b256, 0, stream>>>(o2bf, Wout, 8192, 1024, 1024, x1, x);
  ln2_k<<<8192, b256, 0, stream>>>(x1, cn_w, cn_b, zbf);
  gemm_bt<3><<<dim3(44, 64), b256, 0, stream>>>(zbf, Wl12, 8192, 5632, 1024, nullptr, nullptr, pbf, nullptr);
  gemm_bt64<2><<<dim3(16, 64), b256, 0, stream>>>(pbf, Wl3, 8192, 1024, 2816, out, x1);
}

// Round 7
// 656.702 us; speedup vs baseline: 1.9932x; 1.0583x over previous
//
#include <hip/hip_runtime.h>

// MetaLA decoder layer on gfx950.
// R7: scan parallelism doubled: NC 32 -> 64 (CHK 32), 4096 waves = 4/SIMD
//     (T grows to 33.6 MB, aliased onto the pbf region which is dead during
//     the scan); ts loops unroll 2 so next-iter uniform e/q s_loads issue
//     during current-iter compute. GEMMs unchanged from R6.

#define Lseq 2048
#define Bb 4
#define Dd 1024
#define Hh 16
#define GLUD 2816
#define NC 64
#define CHK 32

typedef float f32x4 __attribute__((ext_vector_type(4)));
typedef __bf16 bf16x8 __attribute__((ext_vector_type(8)));
typedef unsigned short u16;
typedef u16 u16x8 __attribute__((ext_vector_type(8)));

__device__ __forceinline__ u16 f2bf(float f) {
  unsigned int u = __float_as_uint(f);
  u += 0x7fffu + ((u >> 16) & 1u);
  return (u16)(u >> 16);
}
__device__ __forceinline__ float bf2f(u16 b) {
  return __uint_as_float(((unsigned int)b) << 16);
}

// swizzled column index: rotate 16B sub-chunks within each 32-elem k-group by (row>>1)
__device__ __forceinline__ int swz(int col, int row) {
  return (col & ~31) | ((((col >> 3) + (row >> 1)) & 3) << 3) | (col & 7);
}

__device__ __forceinline__ void gll16(const void* g, void* l) {
  __builtin_amdgcn_global_load_lds((const __attribute__((address_space(1))) void*)g,
                                   (__attribute__((address_space(3))) void*)l, 16, 0, 0);
}

__device__ __forceinline__ float block_sum(float v, float* red) {
#pragma unroll
  for (int o = 32; o > 0; o >>= 1) v += __shfl_down(v, o);
  __syncthreads();
  if ((threadIdx.x & 63) == 0) red[threadIdx.x >> 6] = v;
  __syncthreads();
  return red[0] + red[1] + red[2] + red[3];
}

// ---------------- LN1: x (L,B,D) -> h (B,L,D) bf16 ----------------
__global__ __launch_bounds__(256) void ln1_k(const float* __restrict__ x,
                                             const float* __restrict__ w,
                                             const float* __restrict__ bia,
                                             u16* __restrict__ h) {
  __shared__ float red[4];
  int r = blockIdx.x;           // r = l*B + b
  int l = r >> 2, bb = r & 3;
  const float* xr = x + (size_t)r * Dd;
  int d0 = threadIdx.x * 4;
  float4 xv = *(const float4*)&xr[d0];
  float mean = block_sum(xv.x + xv.y + xv.z + xv.w, red) * (1.f / Dd);
  float a0 = xv.x - mean, a1 = xv.y - mean, a2 = xv.z - mean, a3 = xv.w - mean;
  float var = block_sum(a0 * a0 + a1 * a1 + a2 * a2 + a3 * a3, red) * (1.f / Dd);
  float rs = rsqrtf(var + 1e-5f);
  ushort4 ov;
  ov.x = f2bf(a0 * rs * w[d0 + 0] + bia[d0 + 0]);
  ov.y = f2bf(a1 * rs * w[d0 + 1] + bia[d0 + 1]);
  ov.z = f2bf(a2 * rs * w[d0 + 2] + bia[d0 + 2]);
  ov.w = f2bf(a3 * rs * w[d0 + 3] + bia[d0 + 3]);
  *(ushort4*)&h[((size_t)(bb * Lseq + l)) * Dd + d0] = ov;
}

// ---------------- LN2: x1 (row r) -> z bf16 swizzled ----------------
__global__ __launch_bounds__(256) void ln2_k(const float* __restrict__ x1,
                                             const float* __restrict__ w,
                                             const float* __restrict__ bia,
                                             u16* __restrict__ z) {
  __shared__ float red[4];
  int r = blockIdx.x;
  const float* xr = x1 + (size_t)r * Dd;
  int d0 = threadIdx.x * 4;
  float4 xv = *(const float4*)&xr[d0];
  float mean = block_sum(xv.x + xv.y + xv.z + xv.w, red) * (1.f / Dd);
  float a0 = xv.x - mean, a1 = xv.y - mean, a2 = xv.z - mean, a3 = xv.w - mean;
  float var = block_sum(a0 * a0 + a1 * a1 + a2 * a2 + a3 * a3, red) * (1.f / Dd);
  float rs = rsqrtf(var + 1e-5f);
  ushort4 o;
  o.x = f2bf(a0 * rs * w[d0 + 0] + bia[d0 + 0]);
  o.y = f2bf(a1 * rs * w[d0 + 1] + bia[d0 + 1]);
  o.z = f2bf(a2 * rs * w[d0 + 2] + bia[d0 + 2]);
  o.w = f2bf(a3 * rs * w[d0 + 3] + bia[d0 + 3]);
  int dcol = (d0 & ~31) | ((((d0 >> 3) + (r >> 1)) & 3) << 3) | (d0 & 7);
  *(ushort4*)&z[(size_t)r * Dd + dcol] = o;
}

// ------------- conv4 causal + SiLU: h bf16 -> y bf16 swizzled (B*L, D) -------------
__global__ __launch_bounds__(256) void conv_k(const u16* __restrict__ h,
                                              const float* __restrict__ cw,
                                              u16* __restrict__ ybf) {
  int m = blockIdx.x;           // m = b*L + l
  int b = m >> 11, l = m & (Lseq - 1);
  int d0 = threadIdx.x * 4;
  float4 acc = {0.f, 0.f, 0.f, 0.f};
  const u16* hb = h + ((size_t)b * Lseq) * Dd + d0;
#pragma unroll
  for (int w = 0; w < 4; w++) {
    int ll = l - 3 + w;
    if (ll >= 0) {
      ushort4 hv = *(const ushort4*)&hb[(size_t)ll * Dd];
      acc.x += bf2f(hv.x) * cw[(d0 + 0) * 4 + w];
      acc.y += bf2f(hv.y) * cw[(d0 + 1) * 4 + w];
      acc.z += bf2f(hv.z) * cw[(d0 + 2) * 4 + w];
      acc.w += bf2f(hv.w) * cw[(d0 + 3) * 4 + w];
    }
  }
  ushort4 o;
  o.x = f2bf(acc.x / (1.f + expf(-acc.x)));
  o.y = f2bf(acc.y / (1.f + expf(-acc.y)));
  o.z = f2bf(acc.z / (1.f + expf(-acc.z)));
  o.w = f2bf(acc.w / (1.f + expf(-acc.w)));
  int dcol = (d0 & ~31) | ((((d0 >> 3) + (m >> 1)) & 3) << 3) | (d0 & 7);
  *(ushort4*)&ybf[(size_t)m * Dd + dcol] = o;
}

// -------- fused weight prep: transpose + bf16 + swizzle (+Wl12 interleave) --------
__global__ __launch_bounds__(256) void prep_k(const float* __restrict__ q_w,
                                              const float* __restrict__ kg_w,
                                              const float* __restrict__ v_w,
                                              const float* __restrict__ g_w,
                                              const float* __restrict__ out_w,
                                              const float* __restrict__ l1_w,
                                              const float* __restrict__ l2_w,
                                              const float* __restrict__ l3_w,
                                              u16* __restrict__ Wqkvg,
                                              u16* __restrict__ Wout,
                                              u16* __restrict__ Wl12,
                                              u16* __restrict__ Wl3) {
  __shared__ float tile[32][33];
  int blk = blockIdx.x;
  const float* src;
  u16* dst;
  int R, C, ilv = 0, off = 0, base;
  if (blk < 512)       { src = q_w;   dst = Wqkvg;              R = 1024; C = 512;  base = 0; }
  else if (blk < 1024) { src = kg_w;  dst = Wqkvg + 512 * 1024; R = 1024; C = 512;  base = 512; }
  else if (blk < 2048) { src = v_w;   dst = Wqkvg + 1024 * 1024; R = 1024; C = 1024; base = 1024; }
  else if (blk < 3072) { src = g_w;   dst = Wqkvg + 2048 * 1024; R = 1024; C = 1024; base = 2048; }
  else if (blk < 4096) { src = out_w; dst = Wout;               R = 1024; C = 1024; base = 3072; }
  else if (blk < 6912) { src = l1_w;  dst = Wl12; R = 1024; C = 2816; ilv = 1; off = 0; base = 4096; }
  else if (blk < 9728) { src = l2_w;  dst = Wl12; R = 1024; C = 2816; ilv = 1; off = 1; base = 6912; }
  else                 { src = l3_w;  dst = Wl3;  R = 2816; C = 1024; base = 9728; }
  int local = blk - base;
  int ct = C >> 5;
  int bx = local % ct, by = local / ct;
  int tx = threadIdx.x & 31, ty = threadIdx.x >> 5;  // 32x8
  int c0 = bx * 32, r0 = by * 32;
#pragma unroll
  for (int k = 0; k < 4; k++)
    tile[ty + 8 * k][tx] = src[(size_t)(r0 + ty + 8 * k) * C + c0 + tx];
  __syncthreads();
#pragma unroll
  for (int k = 0; k < 4; k++) {
    int c = c0 + ty + 8 * k;
    int dstrow = ilv ? (((c >> 4) << 5) + off * 16 + (c & 15)) : c;
    int kpos = r0 + tx;
    dst[(size_t)dstrow * R + swz(kpos, dstrow)] = f2bf(tile[tx][ty + 8 * k]);
  }
}

// ---- pass A: per-chunk T (32x64) and decay product P (32); 4 waves = 4 chunks ----
__global__ __launch_bounds__(256) void passA_k(const float* __restrict__ decay,
                                               const u16* __restrict__ qkvg16,
                                               float* __restrict__ T,
                                               float* __restrict__ P) {
  int wave = __builtin_amdgcn_readfirstlane((int)(threadIdx.x >> 6));
  int lane = threadIdx.x & 63;
  int c = blockIdx.x * 4 + wave, bh = blockIdx.y;
  int b = bh >> 4, h = bh & 15;
  size_t t0 = (size_t)b * Lseq + c * CHK;        // first timestep row
  const float* ep = decay + t0 * 512 + h * 32;   // wave-uniform base -> s_load
  const u16* vp = qkvg16 + t0 * 3072 + 1024 + h * 64 + lane;
  const float* dp = decay + t0 * 512 + h * 32 + (lane & 31);
  float S[32];
#pragma unroll
  for (int i = 0; i < 32; i++) S[i] = 0.f;
  float p = 1.f;
  u16 vnext = vp[0];
  float dnext = dp[0];
#pragma unroll 2
  for (int ts = 0; ts < CHK; ts++) {
    float vj = bf2f(vnext), dl = dnext;
    int tn = (ts + 1 < CHK) ? ts + 1 : ts;
    vnext = vp[(size_t)tn * 3072];
    dnext = dp[(size_t)tn * 512];
    const float* e = ep + (size_t)ts * 512;
    p *= dl;
#pragma unroll
    for (int i = 0; i < 32; i++) {
      float ei = e[i];
      float kv = (1.f - ei) * vj;
      S[i] = ei * S[i] + kv;
    }
  }
  float* Tc = T + ((size_t)bh * NC + c) * 2048;
#pragma unroll
  for (int i = 0; i < 32; i++) Tc[i * 64 + lane] = S[i];
  if (lane < 32) P[((size_t)bh * NC + c) * 32 + lane] = p;
}

// ---- pass B: sequential cross-chunk propagation (Sg aliases T; read-first) ----
__global__ __launch_bounds__(256) void passB_k(const float* __restrict__ T,
                                               const float* __restrict__ P,
                                               float* __restrict__ Sg) {
  int bh = blockIdx.x >> 3;
  int f = (blockIdx.x & 7) * 256 + threadIdx.x;  // 0..2047
  int i = f >> 6;
  float s = 0.f;
  for (int c = 0; c < NC; c++) {
    size_t base = ((size_t)bh * NC + c) * 2048 + f;
    float pc = P[((size_t)bh * NC + c) * 32 + i];
    float tv = T[base];
    Sg[base] = s;                        // state at chunk start (aliases T[c])
    s = pc * s + tv;
  }
}

// ---- pass C fused: scan + aug sigmoid + groupnorm(64) + silu(g) -> o2 bf16 swz ----
__global__ __launch_bounds__(256) void passC_k(const float* __restrict__ decay,
                                               const u16* __restrict__ qkvg16,
                                               const float* __restrict__ Sg,
                                               const float* __restrict__ aug,
                                               const float* __restrict__ gb,
                                               u16* __restrict__ o2) {
  int wave = __builtin_amdgcn_readfirstlane((int)(threadIdx.x >> 6));
  int lane = threadIdx.x & 63;
  int c = blockIdx.x * 4 + wave, bh = blockIdx.y;
  int b = bh >> 4, h = bh & 15;
  size_t t0 = (size_t)b * Lseq + c * CHK;
  const float* ep = decay + t0 * 512 + h * 32;                                  // uniform
  const unsigned int* qp = (const unsigned int*)(qkvg16 + t0 * 3072 + h * 32);  // uniform
  const u16* vp = qkvg16 + t0 * 3072 + 1024 + h * 64 + lane;
  const u16* gp = qkvg16 + t0 * 3072 + 2048 + h * 64 + lane;
  float S[32];
  const float* Sgc = Sg + ((size_t)bh * NC + c) * 2048;
#pragma unroll
  for (int i = 0; i < 32; i++) S[i] = Sgc[i * 64 + lane];
  float vaug[32];
#pragma unroll
  for (int i = 0; i < 32; i++) vaug[i] = aug[h * 32 + i];
  float gbv = gb[h * 64 + lane];
  int colbase = h * 64 + lane;
  int colfix = (colbase & ~31) | (colbase & 7);
  int colrot0 = colbase >> 3;
  u16 vnext = vp[0], gnext = gp[0];
#pragma unroll 2
  for (int ts = 0; ts < CHK; ts++) {
    float vj = bf2f(vnext);
    float gg = bf2f(gnext) + gbv;
    int tn = (ts + 1 < CHK) ? ts + 1 : ts;
    vnext = vp[(size_t)tn * 3072];
    gnext = gp[(size_t)tn * 3072];
    const float* e = ep + (size_t)ts * 512;
    const unsigned int* q = qp + (size_t)ts * 1536;
    float a0 = 0.f, a1 = 0.f, aw = 0.f;
#pragma unroll
    for (int i = 0; i < 32; i += 2) {
      unsigned int qq = q[i >> 1];
      float q0 = __uint_as_float(qq << 16);
      float q1 = __uint_as_float(qq & 0xffff0000u);
      float e0 = e[i], e1 = e[i + 1];
      float k0 = 1.f - e0, k1 = 1.f - e1;
      S[i + 0] = e0 * S[i + 0] + k0 * vj; a0 += q0 * S[i + 0];
      S[i + 1] = e1 * S[i + 1] + k1 * vj; a1 += q1 * S[i + 1];
      aw += q0 * vaug[i] * k0 + q1 * vaug[i + 1] * k1;
    }
    float o = (a0 + a1) + 1.f / (1.f + expf(-aw * vj));
    // groupnorm over the 64 lanes (head dim)
    float s = o;
#pragma unroll
    for (int d = 1; d < 64; d <<= 1) s += __shfl_xor(s, d);
    float dcen = o - s * (1.f / 64.f);
    float ss = dcen * dcen;
#pragma unroll
    for (int d = 1; d < 64; d <<= 1) ss += __shfl_xor(ss, d);
    float rs = rsqrtf(ss * (1.f / 64.f) + 1e-5f);
    float res = (gg / (1.f + expf(-gg))) * dcen * rs;
    int m = (int)t0 + ts;
    int dcol = colfix | (((colrot0 + (m >> 1)) & 3) << 3);
    o2[(size_t)m * 1024 + dcol] = f2bf(res);
  }
}

// ---------------- bf16 MFMA GEMM 128x128: C(MxN) = A(MxK) * B(NxK)^T ----------------
// EPI 0: cols [512,1024) -> decay fp32; else Cbf[row*N+col] = bf16(v)  (q/v/g)
// EPI 3: GLU, Wl12 16-interleaved: u1=acc[tm][2t], u2=acc[tm][2t+1] (same lane)
template <int EPI>
__global__ __launch_bounds__(256) void gemm_bt(const u16* __restrict__ A,
                                               const u16* __restrict__ B,
                                               int M, int N, int K,
                                               float* __restrict__ Cf,
                                               const float* __restrict__ addsrc,
                                               u16* __restrict__ Cbf,
                                               float* __restrict__ decayp) {
  __shared__ __align__(16) u16 lA[2 * 4096];   // [half g][128 rows][32 k]
  __shared__ __align__(16) u16 lB[2 * 4096];
  const int tid = threadIdx.x;
  const int wave = tid >> 6, lane = tid & 63;
  const int m0 = blockIdx.y * 128, n0 = blockIdx.x * 128;
  const int wm = wave & 1, wn = wave >> 1;
  f32x4 acc[4][4];
#pragma unroll
  for (int a = 0; a < 4; a++)
#pragma unroll
    for (int b = 0; b < 4; b++) acc[a][b] = {0.f, 0.f, 0.f, 0.f};

  const int srow = lane >> 2;          // staging: instr j covers rows j*16..+16
  const int sk8 = (lane & 3) * 8;
  const int rsel = lane & 15;
  const int rot = (((lane >> 4) + (rsel >> 1)) & 3) << 3;  // swizzled k-chunk
  for (int k0 = 0; k0 < K; k0 += 64) {
    __syncthreads();
#pragma unroll
    for (int g = 0; g < 2; g++) {
#pragma unroll
      for (int it = 0; it < 2; it++) {
        int j = wave * 2 + it;
        int row = j * 16 + srow;
        gll16(A + (size_t)(m0 + row) * K + k0 + g * 32 + sk8, &lA[g * 4096 + j * 512]);
        gll16(B + (size_t)(n0 + row) * K + k0 + g * 32 + sk8, &lB[g * 4096 + j * 512]);
      }
    }
    __syncthreads();
#pragma unroll
    for (int g = 0; g < 2; g++) {
      bf16x8 af[4], bfr[4];
#pragma unroll
      for (int t = 0; t < 4; t++) {
        af[t] = __builtin_bit_cast(bf16x8,
                 *(const u16x8*)&lA[g * 4096 + (wm * 64 + t * 16 + rsel) * 32 + rot]);
        bfr[t] = __builtin_bit_cast(bf16x8,
                 *(const u16x8*)&lB[g * 4096 + (wn * 64 + t * 16 + rsel) * 32 + rot]);
      }
#pragma unroll
      for (int tm = 0; tm < 4; tm++)
#pragma unroll
        for (int tn = 0; tn < 4; tn++)
          acc[tm][tn] = __builtin_amdgcn_mfma_f32_16x16x32_bf16(af[tm], bfr[tn], acc[tm][tn], 0, 0, 0);
    }
  }

  const int rquad = (lane >> 4) * 4;
  const int csel = lane & 15;
#pragma unroll
  for (int tm = 0; tm < 4; tm++) {
    int rowb = m0 + wm * 64 + tm * 16 + rquad;
#pragma unroll
    for (int tn = 0; tn < 4; tn++) {
      int col = n0 + wn * 64 + tn * 16 + csel;
#pragma unroll
      for (int r = 0; r < 4; r++) {
        float v = acc[tm][tn][r];
        int row = rowb + r;
        if (EPI == 0) {
          if (col >= 512 && col < 1024) {
            float sg = 1.f / (1.f + expf(-v));
            decayp[(size_t)row * 512 + (col - 512)] = expf(0.0625f * logf(sg));
          } else {
            Cbf[(size_t)row * N + col] = f2bf(v);
          }
        } else {
          if ((tn & 1) == 0) {
            float u2 = acc[tm][tn + 1][r];
            float p = (v / (1.f + expf(-v))) * u2;
            int oc = (n0 >> 1) + wn * 32 + ((tn >> 1) << 4) + csel;
            Cbf[(size_t)row * (N >> 1) + swz(oc, row)] = f2bf(p);
          }
        }
      }
    }
  }
}

// ---------------- bf16 MFMA GEMM 128x64 (4 blocks/CU for small-N GEMMs) ----------------
// EPI 1: Cf[(l*B+b)*D+col] = v + addsrc[same]   (row = b*L+l)
// EPI 2: Cf[row*D+col] = v + addsrc[same]
template <int EPI>
__global__ __launch_bounds__(256) void gemm_bt64(const u16* __restrict__ A,
                                                 const u16* __restrict__ B,
                                                 int M, int N, int K,
                                                 float* __restrict__ Cf,
                                                 const float* __restrict__ addsrc) {
  __shared__ __align__(16) u16 lA[2 * 4096];   // [half][128 rows][32 k]
  __shared__ __align__(16) u16 lB[2 * 2048];   // [half][64 rows][32 k]
  const int tid = threadIdx.x;
  const int wave = tid >> 6, lane = tid & 63;
  const int m0 = blockIdx.y * 128, n0 = blockIdx.x * 64;
  const int wm = wave & 1, wn = wave >> 1;     // 2x2: 64 rows x 32 cols per wave
  f32x4 acc[4][2];
#pragma unroll
  for (int a = 0; a < 4; a++)
#pragma unroll
    for (int b = 0; b < 2; b++) acc[a][b] = {0.f, 0.f, 0.f, 0.f};

  const int srow = lane >> 2;
  const int sk8 = (lane & 3) * 8;
  const int rsel = lane & 15;
  const int rot = (((lane >> 4) + (rsel >> 1)) & 3) << 3;
  for (int k0 = 0; k0 < K; k0 += 64) {
    __syncthreads();
#pragma unroll
    for (int g = 0; g < 2; g++) {
#pragma unroll
      for (int it = 0; it < 2; it++) {       // A: 8 instrs over 4 waves
        int j = wave * 2 + it;
        int row = j * 16 + srow;
        gll16(A + (size_t)(m0 + row) * K + k0 + g * 32 + sk8, &lA[g * 4096 + j * 512]);
      }
      {                                      // B: 4 instrs over 4 waves
        int row = wave * 16 + srow;
        gll16(B + (size_t)(n0 + row) * K + k0 + g * 32 + sk8, &lB[g * 2048 + wave * 512]);
      }
    }
    __syncthreads();
#pragma unroll
    for (int g = 0; g < 2; g++) {
      bf16x8 af[4], bfr[2];
#pragma unroll
      for (int t = 0; t < 4; t++)
        af[t] = __builtin_bit_cast(bf16x8,
                 *(const u16x8*)&lA[g * 4096 + (wm * 64 + t * 16 + rsel) * 32 + rot]);
#pragma unroll
      for (int t = 0; t < 2; t++)
        bfr[t] = __builtin_bit_cast(bf16x8,
                 *(const u16x8*)&lB[g * 2048 + (wn * 32 + t * 16 + rsel) * 32 + rot]);
#pragma unroll
      for (int tm = 0; tm < 4; tm++)
#pragma unroll
        for (int tn = 0; tn < 2; tn++)
          acc[tm][tn] = __builtin_amdgcn_mfma_f32_16x16x32_bf16(af[tm], bfr[tn], acc[tm][tn], 0, 0, 0);
    }
  }

  const int rquad = (lane >> 4) * 4;
  const int csel = lane & 15;
#pragma unroll
  for (int tm = 0; tm < 4; tm++) {
    int rowb = m0 + wm * 64 + tm * 16 + rquad;
#pragma unroll
    for (int tn = 0; tn < 2; tn++) {
      int col = n0 + wn * 32 + tn * 16 + csel;
#pragma unroll
      for (int r = 0; r < 4; r++) {
        float v = acc[tm][tn][r];
        int row = rowb + r;
        if (EPI == 1) {
          int l = row & (Lseq - 1), bb = row >> 11;
          size_t o = ((size_t)(l * Bb + bb)) * Dd + col;
          Cf[o] = v + addsrc[o];
        } else {
          size_t o = (size_t)row * Dd + col;
          Cf[o] = v + addsrc[o];
        }
      }
    }
  }
}

extern "C" void kernel_launch(void* const* d_in, const int* in_sizes, int n_in,
                              void* d_out, int out_size, void* d_ws, size_t ws_size,
                              hipStream_t stream) {
  const float* x = (const float*)d_in[0];
  const float* tn_w = (const float*)d_in[1];
  const float* tn_b = (const float*)d_in[2];
  const float* conv_w = (const float*)d_in[3];
  const float* q_w = (const float*)d_in[4];
  const float* kg_w = (const float*)d_in[5];
  const float* v_w = (const float*)d_in[6];
  const float* g_w = (const float*)d_in[7];
  const float* g_b = (const float*)d_in[8];
  const float* out_w = (const float*)d_in[9];
  const float* aug = (const float*)d_in[10];
  const float* cn_w = (const float*)d_in[11];
  const float* cn_b = (const float*)d_in[12];
  const float* l1_w = (const float*)d_in[13];
  const float* l2_w = (const float*)d_in[14];
  const float* l3_w = (const float*)d_in[15];
  float* out = (float*)d_out;
  char* ws = (char*)d_ws;

  // workspace layout (<= 206.4 MB); regions reused across stage lifetimes
  u16* Wqkvg = (u16*)(ws + 0);                 // 6 MB   (3072 x 1024)
  u16* Wout = (u16*)(ws + 6291456);            // 2 MB
  u16* Wl12 = (u16*)(ws + 8388608);            // 11 MB  (5632 x 1024, 16-interleaved)
  u16* Wl3 = (u16*)(ws + 19922944);            // 5.5 MB (1024 x 2816)
  u16* hbuf = (u16*)(ws + 25690112);           // 32 MB region: h bf16 -> x1 fp32
  float* x1 = (float*)(ws + 25690112);
  u16* ybf = (u16*)(ws + 59244544);            // 16 MB: ybf -> o2bf
  u16* o2bf = (u16*)(ws + 59244544);
  u16* qkvg16 = (u16*)(ws + 76021760);         // 48 MB bf16 q/v/g -> zbf after scan
  u16* zbf = (u16*)(ws + 76021760);
  u16* pbf = (u16*)(ws + 126353408);           // 46.1 MB GLU out; T/Sg alias (scan only)
  float* Tbuf = (float*)(ws + 126353408);      // 33.6 MB (dead once passC done)
  float* Sg = Tbuf;
  float* Pbuf = (float*)(ws + 159907840);      // 512 KB (within pbf region)
  float* decay = (float*)(ws + 172490752);     // 16 MB fp32

  dim3 b256(256);
  prep_k<<<12544, b256, 0, stream>>>(q_w, kg_w, v_w, g_w, out_w, l1_w, l2_w, l3_w,
                                     Wqkvg, Wout, Wl12, Wl3);
  ln1_k<<<8192, b256, 0, stream>>>(x, tn_w, tn_b, hbuf);
  conv_k<<<8192, b256, 0, stream>>>(hbuf, conv_w, ybf);
  gemm_bt<0><<<dim3(24, 64), b256, 0, stream>>>(ybf, Wqkvg, 8192, 3072, 1024, nullptr, nullptr, qkvg16, decay);
  passA_k<<<dim3(NC / 4, 64), b256, 0, stream>>>(decay, qkvg16, Tbuf, Pbuf);
  passB_k<<<512, b256, 0, stream>>>(Tbuf, Pbuf, Sg);
  passC_k<<<dim3(NC / 4, 64), b256, 0, stream>>>(decay, qkvg16, Sg, aug, g_b, o2bf);
  gemm_bt64<1><<<dim3(16, 64), b256, 0, stream>>>(o2bf, Wout, 8192, 1024, 1024, x1, x);
  ln2_k<<<8192, b256, 0, stream>>>(x1, cn_w, cn_b, zbf);
  gemm_bt<3><<<dim3(44, 64), b256, 0, stream>>>(zbf, Wl12, 8192, 5632, 1024, nullptr, nullptr, pbf, nullptr);
  gemm_bt64<2><<<dim3(16, 64), b256, 0, stream>>>(pbf, Wl3, 8192, 1024, 2816, out, x1);
}